// Round 15
// baseline (674.162 us; speedup 1.0000x reference)
//
#include <hip/hip_runtime.h>
#include <math.h>

// ---------------------------------------------------------------------------
// CoLT5 MoE layer, round 15 (base = round 14, 586us):
//  - scatter_y: 128x512 tiles (was 128x256) -> h re-stream factor 4x -> 2x
//    (R12/R13/R14 A/B: scatter is traffic-bound, insensitive to occupancy
//    and dbuf; 317MB FETCH vs 128MB compulsory was the limiter).
//    8 waves 2Mx4N (wave 64x128), acc[4][8], 80KB LDS single-buffered.
//  - gather: unchanged R12 single-buffer (occupancy-sensitive, proven).
//  - rest identical (atomic-free scatter, bf16 yout aliasing We1T, ~211MB
//    merged layout, R10 atomic fallback).
// Shapes hard-coded: T=8192, D=1024, D2=2048, H=4096, E=4.
// ---------------------------------------------------------------------------

typedef short bf16x8 __attribute__((ext_vector_type(8)));
typedef float f32x4 __attribute__((ext_vector_type(4)));
typedef unsigned short u16;

__device__ __forceinline__ u16 f2bf(float f) {
  unsigned u = __float_as_uint(f);
  u += 0x7FFFu + ((u >> 16) & 1u);  // round-to-nearest-even
  return (u16)(u >> 16);
}
__device__ __forceinline__ float bf2f(u16 s) {
  return __uint_as_float(((unsigned)s) << 16);
}
// exact gelu (router path: logit precision decides top-2 ordering)
__device__ __forceinline__ float gelu_f(float x) {
  return 0.5f * x * (1.0f + erff(x * 0.70710678118654752f));
}
// fast gelu (expert path; |err|<=3e-3 << 0.119 threshold)
__device__ __forceinline__ float gelu_fast(float x) {
  float y = 1.5957691216057308f * (x + 0.044715f * x * x * x);
  float e = __expf(y);
  float t = 1.0f - 2.0f * __builtin_amdgcn_rcpf(e + 1.0f);
  return 0.5f * x * (1.0f + t);
}
__device__ __forceinline__ void gload_lds16(const void* g, void* l) {
  __builtin_amdgcn_global_load_lds(
      (const __attribute__((address_space(1))) void*)g,
      (__attribute__((address_space(3))) void*)l, 16, 0, 0);
}

// ---------------------------------------------------------------------------
// x (fp32) -> x_hi (bf16) + x_lo (bf16 residual)
// ---------------------------------------------------------------------------
__global__ __launch_bounds__(256) void convert_split_kernel(
    const float* __restrict__ in, u16* __restrict__ hi, u16* __restrict__ lo,
    int n4) {
  int i = blockIdx.x * blockDim.x + threadIdx.x;
  int stride = gridDim.x * blockDim.x;
  for (; i < n4; i += stride) {
    float4 v = ((const float4*)in)[i];
    float f[4] = {v.x, v.y, v.z, v.w};
    ushort4 h4, l4;
    u16* hp = (u16*)&h4;
    u16* lp = (u16*)&l4;
#pragma unroll
    for (int u = 0; u < 4; ++u) {
      u16 h = f2bf(f[u]);
      hp[u] = h;
      lp[u] = f2bf(f[u] - bf2f(h));
    }
    ((ushort4*)hi)[i] = h4;
    ((ushort4*)lo)[i] = l4;
  }
}

// ---------------------------------------------------------------------------
// transpose fp32 [R][C] -> bf16 [C][R] hi + lo residual (for rW1)
// ---------------------------------------------------------------------------
__global__ __launch_bounds__(256) void transpose_split_kernel(
    const float* __restrict__ in, u16* __restrict__ hi, u16* __restrict__ lo,
    int R, int C) {
  __shared__ float tile[32][33];
  const int c0 = blockIdx.x * 32, r0 = blockIdx.y * 32;
#pragma unroll
  for (int i = 0; i < 4; ++i) {
    int rr = threadIdx.y + i * 8;
    tile[rr][threadIdx.x] = in[(size_t)(r0 + rr) * C + c0 + threadIdx.x];
  }
  __syncthreads();
#pragma unroll
  for (int i = 0; i < 4; ++i) {
    int cc = threadIdx.y + i * 8;
    float v = tile[threadIdx.x][cc];
    u16 h = f2bf(v);
    size_t oidx = (size_t)(c0 + cc) * R + r0 + threadIdx.x;
    hi[oidx] = h;
    lo[oidx] = f2bf(v - bf2f(h));
  }
}

// ---------------------------------------------------------------------------
// expert-weight transpose pair; grid (8192, nE), y = expert slot.
// ---------------------------------------------------------------------------
__global__ __launch_bounds__(256) void transpose_pair_kernel(
    const float* __restrict__ We1, const float* __restrict__ We2,
    u16* __restrict__ T1, u16* __restrict__ T2, size_t tstride, int e0) {
  __shared__ float tile[32][33];
  const int e = e0 + blockIdx.y;
  int b = blockIdx.x;
  const float* in;
  u16* out;
  int R, C, tx, ty;
  if (b < 4096) {
    in = We1 + (size_t)e * 1024 * 4096;
    out = T1 + (size_t)blockIdx.y * tstride;
    R = 1024; C = 4096; tx = b & 127; ty = b >> 7;
  } else {
    b -= 4096;
    in = We2 + (size_t)e * 1024 * 4096;
    out = T2 + (size_t)blockIdx.y * tstride;
    R = 4096; C = 1024; tx = b & 31; ty = b >> 5;
  }
  const int c0 = tx * 32, r0 = ty * 32;
#pragma unroll
  for (int i = 0; i < 4; ++i) {
    int rr = threadIdx.y + i * 8;
    tile[rr][threadIdx.x] = in[(size_t)(r0 + rr) * C + c0 + threadIdx.x];
  }
  __syncthreads();
#pragma unroll
  for (int i = 0; i < 4; ++i) {
    int cc = threadIdx.y + i * 8;
    out[(size_t)(c0 + cc) * R + r0 + threadIdx.x] = f2bf(tile[threadIdx.x][cc]);
  }
}

// ---------------------------------------------------------------------------
// Fused 3-product split-bf16 router GEMM + partial-logits epilogue (as R7).
// ---------------------------------------------------------------------------
__global__ __launch_bounds__(256) void gemm3_router_kernel(
    const u16* __restrict__ Ahi, const u16* __restrict__ Alo,
    const u16* __restrict__ Bhi, const u16* __restrict__ Blo, int K,
    const float* __restrict__ bias, const float* __restrict__ rW2,
    float* __restrict__ parts) {
  __shared__ alignas(16) u16 Sm[4 * 128 * 32];
  __shared__ float pls[2][128][4];
  const int tid = threadIdx.x;
  const int lane = tid & 63;
  const int w = tid >> 6;
  const int wr = w >> 1, wc = w & 1;

  const int flat = blockIdx.x + blockIdx.y * 16;
  const int swz = (flat & 7) * 128 + (flat >> 3);
  const int bxs = swz & 15;
  const int bys = swz >> 4;
  const int brow = bys * 128;
  const int bcol = bxs * 128;

  f32x4 acc[4][4] = {};
  char* S = (char*)Sm;
  const u16* srcs[4] = {Ahi + (size_t)brow * K, Alo + (size_t)brow * K,
                        Bhi + (size_t)bcol * K, Blo + (size_t)bcol * K};
  const int rA = lane & 15;
  const int kg2 = (lane >> 4) * 16;

  const int nk = K >> 5;
  for (int kt = 0; kt < nk; ++kt) {
    const int k0 = kt << 5;
    __syncthreads();
#pragma unroll
    for (int i = 0; i < 8; ++i) {
      int c = tid + 256 * i;
      int tile = c >> 9;
      int cc = c & 511;
      int row = cc >> 2;
      int kp = (cc & 3) << 3;
      gload_lds16(srcs[tile] + (size_t)row * K + (k0 + kp), S + c * 16);
    }
    __syncthreads();

    bf16x8 ah[4], al[4], bh[4], bl[4];
#pragma unroll
    for (int m = 0; m < 4; ++m) {
      int ro = (wr * 64 + m * 16 + rA) * 64 + kg2;
      ah[m] = *(const bf16x8*)(S + ro);
      al[m] = *(const bf16x8*)(S + 8192 + ro);
    }
#pragma unroll
    for (int n = 0; n < 4; ++n) {
      int ro = (wc * 64 + n * 16 + rA) * 64 + kg2;
      bh[n] = *(const bf16x8*)(S + 16384 + ro);
      bl[n] = *(const bf16x8*)(S + 24576 + ro);
    }
#pragma unroll
    for (int m = 0; m < 4; ++m)
#pragma unroll
      for (int n = 0; n < 4; ++n) {
        acc[m][n] = __builtin_amdgcn_mfma_f32_16x16x32_bf16(ah[m], bh[n], acc[m][n], 0, 0, 0);
        acc[m][n] = __builtin_amdgcn_mfma_f32_16x16x32_bf16(al[m], bh[n], acc[m][n], 0, 0, 0);
        acc[m][n] = __builtin_amdgcn_mfma_f32_16x16x32_bf16(ah[m], bl[n], acc[m][n], 0, 0, 0);
      }
  }

  const int cr = (lane >> 4) * 4;
  const int ccx = lane & 15;
  float4 w2v[4];
  float bv[4];
#pragma unroll
  for (int n = 0; n < 4; ++n) {
    const int gc = bcol + wc * 64 + n * 16 + ccx;
    w2v[n] = ((const float4*)rW2)[gc];
    bv[n] = bias[gc];
  }
#pragma unroll
  for (int m = 0; m < 4; ++m) {
    float pl[4][4];
#pragma unroll
    for (int r = 0; r < 4; ++r)
#pragma unroll
      for (int e = 0; e < 4; ++e) pl[r][e] = 0.f;
#pragma unroll
    for (int n = 0; n < 4; ++n)
#pragma unroll
      for (int r = 0; r < 4; ++r) {
        const float v = gelu_f(acc[m][n][r] + bv[n]);
        pl[r][0] += v * w2v[n].x;
        pl[r][1] += v * w2v[n].y;
        pl[r][2] += v * w2v[n].z;
        pl[r][3] += v * w2v[n].w;
      }
#pragma unroll
    for (int off = 8; off; off >>= 1)
#pragma unroll
      for (int r = 0; r < 4; ++r)
#pragma unroll
        for (int e = 0; e < 4; ++e) pl[r][e] += __shfl_xor(pl[r][e], off);
    if ((lane & 15) == 0) {
      const int row = wr * 64 + m * 16 + cr;
#pragma unroll
      for (int r = 0; r < 4; ++r)
#pragma unroll
        for (int e = 0; e < 4; ++e) pls[wc][row + r][e] = pl[r][e];
    }
  }
  __syncthreads();
  for (int i = tid; i < 512; i += 256) {
    const int row = i >> 2, e = i & 3;
    parts[((size_t)bxs * 8192 + brow + row) * 4 + e] =
        pls[0][row][e] + pls[1][row][e];
  }
}

// ---------------------------------------------------------------------------
// topk: deterministic parts reduce + softmax + top-2 + per-expert lists;
// tokslot[t] = (e1*8192+p1, e2*8192+p2) for the combine pass.
// ---------------------------------------------------------------------------
__global__ __launch_bounds__(256) void topk_kernel(
    const float* __restrict__ parts, const float* __restrict__ rb2,
    float* __restrict__ combine, int* __restrict__ cnt, int* __restrict__ list,
    int2* __restrict__ tokslot, int T) {
  const int t = blockIdx.x * 256 + threadIdx.x;
  const int w = threadIdx.x >> 6, lane = threadIdx.x & 63;
  __shared__ int wpre[4][4];
  __shared__ int gbase[4];

  float lg[4] = {rb2[0], rb2[1], rb2[2], rb2[3]};
#pragma unroll
  for (int s = 0; s < 16; ++s) {
    float4 pv = ((const float4*)parts)[(size_t)s * 8192 + t];
    lg[0] += pv.x;
    lg[1] += pv.y;
    lg[2] += pv.z;
    lg[3] += pv.w;
  }
  float mx = fmaxf(fmaxf(lg[0], lg[1]), fmaxf(lg[2], lg[3]));
  float p[4], sum = 0.f;
#pragma unroll
  for (int e = 0; e < 4; ++e) {
    p[e] = expf(lg[e] - mx);
    sum += p[e];
  }
  float inv = 1.0f / sum;
  int i1 = 0;
#pragma unroll
  for (int e = 1; e < 4; ++e)
    if (lg[e] > lg[i1]) i1 = e;
  int i2 = -1;
#pragma unroll
  for (int e = 0; e < 4; ++e)
    if (e != i1 && (i2 < 0 || lg[e] > lg[i2])) i2 = e;
  float4 cw = {0.f, 0.f, 0.f, 0.f};
  ((float*)&cw)[i1] = p[i1] * inv;
  ((float*)&cw)[i2] = p[i2] * inv;
  ((float4*)combine)[t] = cw;

  unsigned long long m[4];
#pragma unroll
  for (int e = 0; e < 4; ++e) m[e] = __ballot(i1 == e || i2 == e);
  if (lane == 0) {
#pragma unroll
    for (int e = 0; e < 4; ++e) wpre[w][e] = (int)__popcll(m[e]);
  }
  __syncthreads();
  if (threadIdx.x < 4) {
    const int e = threadIdx.x;
    int tot = 0;
#pragma unroll
    for (int ww = 0; ww < 4; ++ww) {
      int c = wpre[ww][e];
      wpre[ww][e] = tot;
      tot += c;
    }
    gbase[e] = atomicAdd(&cnt[e], tot);
  }
  __syncthreads();
  const unsigned long long lt = (1ull << lane) - 1ull;
  int p1 = gbase[i1] + wpre[w][i1] + (int)__popcll(m[i1] & lt);
  list[i1 * 8192 + p1] = t;
  int p2 = gbase[i2] + wpre[w][i2] + (int)__popcll(m[i2] & lt);
  list[i2 * 8192 + p2] = t;
  tokslot[t] = make_int2(i1 * 8192 + p1, i2 * 8192 + p2);
}

// ---------------------------------------------------------------------------
// tiny exclusive prefix over cnt[4] -> pre[4]
// ---------------------------------------------------------------------------
__global__ void prefix_kernel(const int* __restrict__ cnt, int* __restrict__ pre) {
  if (threadIdx.x == 0) {
    int s = 0;
#pragma unroll
    for (int e = 0; e < 4; ++e) {
      pre[e] = s;
      s += cnt[e];
    }
  }
}

// ---------------------------------------------------------------------------
// gather-GEMM (expert GEMM-A): R12 single-buffer version. 128x256 tile,
// 8 waves, BK=64, 48KB LDS (2-3 blocks/CU TLP hides L3-resident latency).
// Octet-XOR coalesced staging.  grid (16, 64, nE).
// ---------------------------------------------------------------------------
__global__ __launch_bounds__(512) void gemm_gather_kernel(
    const u16* __restrict__ A, const u16* __restrict__ WT, size_t wts,
    const int* __restrict__ list, const int* __restrict__ cnt_arr,
    const int* __restrict__ hbase_arr, int e0, const float* __restrict__ be1,
    u16* __restrict__ h) {
  const int K = 1024;
  const int e = e0 + blockIdx.z;
  const int cnt = cnt_arr[e];
  const int rb = blockIdx.y;
  if (rb * 128 >= cnt) return;
  const int hbase = hbase_arr[e];
  const int* lst = list + e * 8192;
  const u16* Bt = WT + (size_t)blockIdx.z * wts;
  const float* bias = be1 + e * 4096;

  __shared__ alignas(16) u16 As[128 * 64];   // 16 KB
  __shared__ alignas(16) u16 Bs[256 * 64];   // 32 KB
  const int tid = threadIdx.x;
  const int lane = tid & 63;
  const int w = tid >> 6;
  const int wr = w >> 2, wc = w & 3;
  const int bcol = blockIdx.x * 256;

  const int srow = tid >> 3;
  const int jx8 = (((tid & 7) ^ (srow & 7)) << 3);
  const u16* aS[2];
  const u16* bS[4];
#pragma unroll
  for (int i = 0; i < 2; ++i) {
    int g = rb * 128 + srow + 64 * i;
    int tok = lst[(g < cnt) ? g : rb * 128];
    aS[i] = A + (size_t)tok * K + jx8;
  }
#pragma unroll
  for (int i = 0; i < 4; ++i)
    bS[i] = Bt + (size_t)(bcol + srow + 64 * i) * K + jx8;
  char* AsB = (char*)As;
  char* BsB = (char*)Bs;
  const int dstb = tid * 16;

  f32x4 acc[4][4] = {};
  const int rA = lane & 15;
  const int ksl = lane >> 4;
  const int rx7 = rA & 7;

  const int nk = K >> 6;  // 16
  for (int kt = 0; kt < nk; ++kt) {
    const int kb = kt << 6;
    __syncthreads();
#pragma unroll
    for (int i = 0; i < 2; ++i)
      gload_lds16(aS[i] + kb, AsB + i * 8192 + dstb);
#pragma unroll
    for (int i = 0; i < 4; ++i)
      gload_lds16(bS[i] + kb, BsB + i * 8192 + dstb);
    __syncthreads();
#pragma unroll
    for (int s = 0; s < 2; ++s) {
      bf16x8 a[4], b[4];
      const int sl = (((s * 4 + ksl) ^ rx7) << 4);
#pragma unroll
      for (int m = 0; m < 4; ++m)
        a[m] = *(const bf16x8*)(AsB + (wr * 64 + m * 16 + rA) * 128 + sl);
#pragma unroll
      for (int n = 0; n < 4; ++n)
        b[n] = *(const bf16x8*)(BsB + (wc * 64 + n * 16 + rA) * 128 + sl);
#pragma unroll
      for (int m = 0; m < 4; ++m)
#pragma unroll
        for (int n = 0; n < 4; ++n)
          acc[m][n] =
              __builtin_amdgcn_mfma_f32_16x16x32_bf16(a[m], b[n], acc[m][n], 0, 0, 0);
    }
  }

  const int cr = (lane >> 4) * 4;
  const int ccx = lane & 15;
#pragma unroll
  for (int m = 0; m < 4; ++m)
#pragma unroll
    for (int n = 0; n < 4; ++n) {
      const int gc = bcol + wc * 64 + n * 16 + ccx;
      const float bv = bias[gc];
#pragma unroll
      for (int r = 0; r < 4; ++r) {
        const int gl = rb * 128 + wr * 64 + m * 16 + cr + r;
        if (gl < cnt)
          h[(size_t)(hbase + gl) * 4096 + gc] = f2bf(gelu_fast(acc[m][n][r] + bv));
      }
    }
}

// ---------------------------------------------------------------------------
// scatter-GEMM, ATOMIC-FREE, 128x512 tile: 8 waves (2Mx4N, wave 64x128),
// BK=64, 80KB LDS single-buffered, K=4096.  grid (2, 64, nE).
// yout[hbase[e]+gl][gc] = bf16(acc + be2[e][gc]).  Halves h re-streaming.
// ---------------------------------------------------------------------------
__global__ __launch_bounds__(512) void gemm_scatter_y_kernel(
    const u16* __restrict__ h, const int* __restrict__ hbase_arr,
    const u16* __restrict__ WT, size_t wts, const int* __restrict__ cnt_arr,
    int e0, const float* __restrict__ be2, u16* __restrict__ yout) {
  const int K = 4096;
  const int e = e0 + blockIdx.z;
  const int cnt = cnt_arr[e];
  const int rb = blockIdx.y;
  if (rb * 128 >= cnt) return;
  const int hbase = hbase_arr[e];
  const u16* Bt = WT + (size_t)blockIdx.z * wts;
  const float* bias = be2 + e * 1024;

  __shared__ alignas(16) u16 As[128 * 64];   // 16 KB
  __shared__ alignas(16) u16 Bs[512 * 64];   // 64 KB
  const int tid = threadIdx.x;
  const int lane = tid & 63;
  const int w = tid >> 6;
  const int wr = w >> 2, wc = w & 3;   // 2M x 4N, wave tile 64 x 128
  const int bcol = blockIdx.x * 512;

  const int srow = tid >> 3;
  const int jx8 = (((tid & 7) ^ (srow & 7)) << 3);
  const u16* aS[2];
  const u16* bS[8];
#pragma unroll
  for (int i = 0; i < 2; ++i)
    aS[i] = h + (size_t)(hbase + rb * 128 + srow + 64 * i) * K + jx8;
#pragma unroll
  for (int i = 0; i < 8; ++i)
    bS[i] = Bt + (size_t)(bcol + srow + 64 * i) * K + jx8;
  char* AsB = (char*)As;
  char* BsB = (char*)Bs;
  const int dstb = tid * 16;

  f32x4 acc[4][8] = {};
  const int rA = lane & 15;
  const int ksl = lane >> 4;
  const int rx7 = rA & 7;

  const int nk = K >> 6;  // 64
  for (int kt = 0; kt < nk; ++kt) {
    const int kb = kt << 6;
    __syncthreads();
#pragma unroll
    for (int i = 0; i < 2; ++i)
      gload_lds16(aS[i] + kb, AsB + i * 8192 + dstb);
#pragma unroll
    for (int i = 0; i < 8; ++i)
      gload_lds16(bS[i] + kb, BsB + i * 8192 + dstb);
    __syncthreads();
#pragma unroll
    for (int s = 0; s < 2; ++s) {
      bf16x8 a[4], b[8];
      const int sl = (((s * 4 + ksl) ^ rx7) << 4);
#pragma unroll
      for (int m = 0; m < 4; ++m)
        a[m] = *(const bf16x8*)(AsB + (wr * 64 + m * 16 + rA) * 128 + sl);
#pragma unroll
      for (int n = 0; n < 8; ++n)
        b[n] = *(const bf16x8*)(BsB + (wc * 128 + n * 16 + rA) * 128 + sl);
#pragma unroll
      for (int m = 0; m < 4; ++m)
#pragma unroll
        for (int n = 0; n < 8; ++n)
          acc[m][n] =
              __builtin_amdgcn_mfma_f32_16x16x32_bf16(a[m], b[n], acc[m][n], 0, 0, 0);
    }
  }

  const int cr = (lane >> 4) * 4;
  const int ccx = lane & 15;
#pragma unroll
  for (int m = 0; m < 4; ++m)
#pragma unroll
    for (int r = 0; r < 4; ++r) {
      const int gl = rb * 128 + wr * 64 + m * 16 + cr + r;
      if (gl >= cnt) continue;
      u16* yrow = yout + (size_t)(hbase + gl) * 1024;
#pragma unroll
      for (int n = 0; n < 8; ++n) {
        const int gc = bcol + wc * 128 + n * 16 + ccx;
        yrow[gc] = f2bf(acc[m][n][r] + bias[gc]);
      }
    }
}

// ---------------------------------------------------------------------------
// combine: out[t] = g1*yout[r1] + g2*yout[r2] (yout bf16); r = prefix[e]+pos.
// ---------------------------------------------------------------------------
__global__ __launch_bounds__(256) void combine_kernel(
    const u16* __restrict__ yout, const int2* __restrict__ tokslot,
    const int* __restrict__ prefix, const float* __restrict__ gates,
    float* __restrict__ out) {
  const int w = threadIdx.x >> 6, lane = threadIdx.x & 63;
  const int t = blockIdx.x * 4 + w;
  const int2 s = tokslot[t];
  const int e1 = s.x >> 13, p1 = s.x & 8191;
  const int e2 = s.y >> 13, p2 = s.y & 8191;
  const int r1 = prefix[e1] + p1;
  const int r2 = prefix[e2] + p2;
  const float g1 = gates[(size_t)t * 4 + e1];
  const float g2 = gates[(size_t)t * 4 + e2];
  const ushort4* y1 = (const ushort4*)(yout + (size_t)r1 * 1024);
  const ushort4* y2 = (const ushort4*)(yout + (size_t)r2 * 1024);
  float4* o = (float4*)(out + (size_t)t * 1024);
#pragma unroll
  for (int j = 0; j < 4; ++j) {
    const int c = lane + j * 64;
    ushort4 a = y1[c], b = y2[c];
    float4 r;
    r.x = g1 * bf2f(a.x) + g2 * bf2f(b.x);
    r.y = g1 * bf2f(a.y) + g2 * bf2f(b.y);
    r.z = g1 * bf2f(a.z) + g2 * bf2f(b.z);
    r.w = g1 * bf2f(a.w) + g2 * bf2f(b.w);
    o[c] = r;
  }
}

// ---------------------------------------------------------------------------
// FALLBACK scatter (atomic, split-K x2) — single-buffered R10 version.
// ---------------------------------------------------------------------------
__global__ __launch_bounds__(512) void gemm_scatter_kernel(
    const u16* __restrict__ h, const int* __restrict__ hbase_arr,
    const u16* __restrict__ WT, size_t wts, const int* __restrict__ list,
    const int* __restrict__ cnt_arr, int e0, const float* __restrict__ be2,
    const float* __restrict__ combine, float* __restrict__ out) {
  const int K = 4096;
  const int zslot = blockIdx.z >> 1;
  const int kz = blockIdx.z & 1;
  const int e = e0 + zslot;
  const int cnt = cnt_arr[e];
  const int rb = blockIdx.y;
  if (rb * 128 >= cnt) return;
  const int hbase = hbase_arr[e];
  const int* lst = list + e * 8192;
  const u16* Bt = WT + (size_t)zslot * wts;
  const float* bias = be2 + e * 1024;
  const int koff = kz * 2048;

  __shared__ alignas(16) u16 As[128 * 64];
  __shared__ alignas(16) u16 Bs[256 * 64];
  const int tid = threadIdx.x;
  const int lane = tid & 63;
  const int w = tid >> 6;
  const int wr = w >> 2, wc = w & 3;
  const int bcol = blockIdx.x * 256;

  const int srow = tid >> 3;
  const int jx8 = (((tid & 7) ^ (srow & 7)) << 3);
  const u16* aS[2];
  const u16* bS[4];
#pragma unroll
  for (int i = 0; i < 2; ++i)
    aS[i] = h + (size_t)(hbase + rb * 128 + srow + 64 * i) * K + koff + jx8;
#pragma unroll
  for (int i = 0; i < 4; ++i)
    bS[i] = Bt + (size_t)(bcol + srow + 64 * i) * K + koff + jx8;
  char* AsB = (char*)As;
  char* BsB = (char*)Bs;
  const int dstb = tid * 16;

  f32x4 acc[4][4] = {};
  const int rA = lane & 15;
  const int ksl = lane >> 4;
  const int rx7 = rA & 7;

  const int nk = 2048 >> 6;
  for (int kt = 0; kt < nk; ++kt) {
    const int kb = kt << 6;
    __syncthreads();
#pragma unroll
    for (int i = 0; i < 2; ++i)
      gload_lds16(aS[i] + kb, AsB + i * 8192 + dstb);
#pragma unroll
    for (int i = 0; i < 4; ++i)
      gload_lds16(bS[i] + kb, BsB + i * 8192 + dstb);
    __syncthreads();
#pragma unroll
    for (int s = 0; s < 2; ++s) {
      bf16x8 a[4], b[4];
      const int sl = (((s * 4 + ksl) ^ rx7) << 4);
#pragma unroll
      for (int m = 0; m < 4; ++m)
        a[m] = *(const bf16x8*)(AsB + (wr * 64 + m * 16 + rA) * 128 + sl);
#pragma unroll
      for (int n = 0; n < 4; ++n)
        b[n] = *(const bf16x8*)(BsB + (wc * 64 + n * 16 + rA) * 128 + sl);
#pragma unroll
      for (int m = 0; m < 4; ++m)
#pragma unroll
        for (int n = 0; n < 4; ++n)
          acc[m][n] =
              __builtin_amdgcn_mfma_f32_16x16x32_bf16(a[m], b[n], acc[m][n], 0, 0, 0);
    }
  }

  const int cr = (lane >> 4) * 4;
  const int ccx = lane & 15;
  const bool addb = (kz == 0);
#pragma unroll
  for (int m = 0; m < 4; ++m)
#pragma unroll
    for (int r = 0; r < 4; ++r) {
      const int gl = rb * 128 + wr * 64 + m * 16 + cr + r;
      if (gl >= cnt) continue;
      const int tok = lst[gl];
      const float gcoef = combine[(size_t)tok * 4 + e];
      float* orow = out + (size_t)tok * 1024;
#pragma unroll
      for (int n = 0; n < 4; ++n) {
        const int gc = bcol + wc * 64 + n * 16 + ccx;
        float v = acc[m][n][r];
        if (addb) v += bias[gc];
        atomicAdd(&orow[gc], gcoef * v);
      }
    }
}

// ---------------------------------------------------------------------------
extern "C" void kernel_launch(void* const* d_in, const int* in_sizes, int n_in,
                              void* d_out, int out_size, void* d_ws,
                              size_t ws_size, hipStream_t stream) {
  const float* x = (const float*)d_in[0];
  const float* rW1 = (const float*)d_in[1];
  const float* rb1 = (const float*)d_in[2];
  const float* rW2 = (const float*)d_in[3];
  const float* rb2 = (const float*)d_in[4];
  const float* We1 = (const float*)d_in[5];
  const float* be1 = (const float*)d_in[6];
  const float* We2 = (const float*)d_in[7];
  const float* be2 = (const float*)d_in[8];
  float* out = (float*)d_out;

  const int T = 8192, D = 1024, D2 = 2048, H = 4096, E = 4;
  const size_t WTS = (size_t)H * D;

  char* ws = (char*)d_ws;
  size_t off = 0;
  auto alloc = [&](size_t bytes) {
    char* p = ws + off;
    off = (off + bytes + 255) & ~(size_t)255;
    return p;
  };
  u16* x_hi = (u16*)alloc((size_t)T * D * 2);            // 16 MB
  float* combine = (float*)alloc((size_t)T * 4 * 4);
  int* cnt = (int*)alloc(256);
  int* prefix = cnt + 4;
  int* list = (int*)alloc((size_t)4 * 8192 * 4);
  int2* tokslot = (int2*)alloc((size_t)T * 8);           // 64 KB
  const size_t common_off = off;

  bool merged;
  u16 *We1T, *We2T, *h, *x_lo, *rW1T_hi, *rW1T_lo, *yout;
  float* parts;
  {
    size_t o = common_off;
    auto a2 = [&](size_t bytes) {
      char* p = ws + o;
      o = (o + bytes + 255) & ~(size_t)255;
      return p;
    };
    u16* w1 = (u16*)a2((size_t)4 * WTS * 2);             // 32 MB
    u16* w2 = (u16*)a2((size_t)4 * WTS * 2);             // 32 MB
    char* hreg = a2((size_t)16384 * H * 2 + (2u << 20)); // 128 MB + 2 MB pad
    merged = (o <= ws_size);  // ~211 MB total — fits (R8-R14)
    if (merged) {
      We1T = w1;
      We2T = w2;
      h = (u16*)hreg;
      yout = w1;  // ALIAS: We1T dead after gather-all; yout = 32 MB bf16
      x_lo = (u16*)hreg;                        // 16 MB (dead before h)
      rW1T_hi = (u16*)(hreg + (16u << 20));     // 4 MB
      rW1T_lo = (u16*)(hreg + (20u << 20));     // 4 MB
      parts = (float*)(hreg + (24u << 20));     // 2 MB
    }
  }
  if (!merged) {
    off = common_off;
    We1T = (u16*)alloc(WTS * 2);
    We2T = (u16*)alloc(WTS * 2);
    x_lo = (u16*)alloc((size_t)T * D * 2);
    rW1T_hi = (u16*)alloc((size_t)D2 * D * 2);
    rW1T_lo = (u16*)alloc((size_t)D2 * D * 2);
    parts = (float*)alloc((size_t)16 * T * 4 * 4);
    h = (u16*)alloc((size_t)T * H * 2);
    yout = nullptr;
  }

  hipMemsetAsync(cnt, 0, 32, stream);
  if (!merged) hipMemsetAsync(out, 0, (size_t)T * D * 4, stream);

  dim3 tb(32, 8);

  convert_split_kernel<<<2048, 256, 0, stream>>>(x, x_hi, x_lo, T * D / 4);
  transpose_split_kernel<<<dim3(D2 / 32, D / 32), tb, 0, stream>>>(
      rW1, rW1T_hi, rW1T_lo, D, D2);
  gemm3_router_kernel<<<dim3(16, 64), 256, 0, stream>>>(
      x_hi, x_lo, rW1T_hi, rW1T_lo, D, rb1, rW2, parts);
  topk_kernel<<<T / 256, 256, 0, stream>>>(parts, rb2, combine, cnt, list,
                                           tokslot, T);

  if (merged) {
    prefix_kernel<<<1, 64, 0, stream>>>(cnt, prefix);
    transpose_pair_kernel<<<dim3(8192, 4), tb, 0, stream>>>(
        We1, We2, We1T, We2T, WTS, 0);
    gemm_gather_kernel<<<dim3(16, 64, 4), 512, 0, stream>>>(
        x_hi, We1T, WTS, list, cnt, prefix, 0, be1, h);
    // yout aliases We1T (dead now); scatter is atomic-free, 128x512 tiles
    gemm_scatter_y_kernel<<<dim3(2, 64, 4), 512, 0, stream>>>(
        h, prefix, We2T, WTS, cnt, 0, be2, yout);
    combine_kernel<<<T / 4, 256, 0, stream>>>(yout, tokslot, prefix, combine,
                                              out);
  } else {
    for (int e = 0; e < E; ++e) {
      transpose_pair_kernel<<<dim3(8192, 1), tb, 0, stream>>>(
          We1, We2, We1T, We2T, 0, e);
      gemm_gather_kernel<<<dim3(16, 64, 1), 512, 0, stream>>>(
          x_hi, We1T, 0, list, cnt, prefix /*zeros*/, e, be1, h);
      gemm_scatter_kernel<<<dim3(4, 64, 2), 512, 0, stream>>>(
          h, prefix /*zeros*/, We2T, 0, list, cnt, e, be2, combine, out);
    }
  }
}

// Round 16
// 621.257 us; speedup vs baseline: 1.0852x; 1.0852x over previous
//
#include <hip/hip_runtime.h>
#include <math.h>

// ---------------------------------------------------------------------------
// CoLT5 MoE layer, round 16 (combining R12-R15 A/B results):
//  - scatter_y: 128x512 tile (2x h-traffic, proven R15: FETCH 317->211MB)
//    PLUS double-buffer 2x80KB=160KB LDS + counted vmcnt(10) (latency hiding,
//    proven R13: dbuf == 2-blk TLP).  R15 regressed only because it had
//    NEITHER TLP (1 blk/CU) nor pipeline (single-buf).
//  - gather: unchanged R12 single-buffer 48KB (occupancy-sensitive, proven).
//  - rest identical (atomic-free scatter, bf16 yout aliasing We1T, ~211MB
//    merged layout, R10 atomic fallback).
// Shapes hard-coded: T=8192, D=1024, D2=2048, H=4096, E=4.
// ---------------------------------------------------------------------------

typedef short bf16x8 __attribute__((ext_vector_type(8)));
typedef float f32x4 __attribute__((ext_vector_type(4)));
typedef unsigned short u16;

__device__ __forceinline__ u16 f2bf(float f) {
  unsigned u = __float_as_uint(f);
  u += 0x7FFFu + ((u >> 16) & 1u);  // round-to-nearest-even
  return (u16)(u >> 16);
}
__device__ __forceinline__ float bf2f(u16 s) {
  return __uint_as_float(((unsigned)s) << 16);
}
// exact gelu (router path: logit precision decides top-2 ordering)
__device__ __forceinline__ float gelu_f(float x) {
  return 0.5f * x * (1.0f + erff(x * 0.70710678118654752f));
}
// fast gelu (expert path; |err|<=3e-3 << 0.119 threshold)
__device__ __forceinline__ float gelu_fast(float x) {
  float y = 1.5957691216057308f * (x + 0.044715f * x * x * x);
  float e = __expf(y);
  float t = 1.0f - 2.0f * __builtin_amdgcn_rcpf(e + 1.0f);
  return 0.5f * x * (1.0f + t);
}
__device__ __forceinline__ void gload_lds16(const void* g, void* l) {
  __builtin_amdgcn_global_load_lds(
      (const __attribute__((address_space(1))) void*)g,
      (__attribute__((address_space(3))) void*)l, 16, 0, 0);
}

// ---------------------------------------------------------------------------
// x (fp32) -> x_hi (bf16) + x_lo (bf16 residual)
// ---------------------------------------------------------------------------
__global__ __launch_bounds__(256) void convert_split_kernel(
    const float* __restrict__ in, u16* __restrict__ hi, u16* __restrict__ lo,
    int n4) {
  int i = blockIdx.x * blockDim.x + threadIdx.x;
  int stride = gridDim.x * blockDim.x;
  for (; i < n4; i += stride) {
    float4 v = ((const float4*)in)[i];
    float f[4] = {v.x, v.y, v.z, v.w};
    ushort4 h4, l4;
    u16* hp = (u16*)&h4;
    u16* lp = (u16*)&l4;
#pragma unroll
    for (int u = 0; u < 4; ++u) {
      u16 h = f2bf(f[u]);
      hp[u] = h;
      lp[u] = f2bf(f[u] - bf2f(h));
    }
    ((ushort4*)hi)[i] = h4;
    ((ushort4*)lo)[i] = l4;
  }
}

// ---------------------------------------------------------------------------
// transpose fp32 [R][C] -> bf16 [C][R] hi + lo residual (for rW1)
// ---------------------------------------------------------------------------
__global__ __launch_bounds__(256) void transpose_split_kernel(
    const float* __restrict__ in, u16* __restrict__ hi, u16* __restrict__ lo,
    int R, int C) {
  __shared__ float tile[32][33];
  const int c0 = blockIdx.x * 32, r0 = blockIdx.y * 32;
#pragma unroll
  for (int i = 0; i < 4; ++i) {
    int rr = threadIdx.y + i * 8;
    tile[rr][threadIdx.x] = in[(size_t)(r0 + rr) * C + c0 + threadIdx.x];
  }
  __syncthreads();
#pragma unroll
  for (int i = 0; i < 4; ++i) {
    int cc = threadIdx.y + i * 8;
    float v = tile[threadIdx.x][cc];
    u16 h = f2bf(v);
    size_t oidx = (size_t)(c0 + cc) * R + r0 + threadIdx.x;
    hi[oidx] = h;
    lo[oidx] = f2bf(v - bf2f(h));
  }
}

// ---------------------------------------------------------------------------
// expert-weight transpose pair; grid (8192, nE), y = expert slot.
// ---------------------------------------------------------------------------
__global__ __launch_bounds__(256) void transpose_pair_kernel(
    const float* __restrict__ We1, const float* __restrict__ We2,
    u16* __restrict__ T1, u16* __restrict__ T2, size_t tstride, int e0) {
  __shared__ float tile[32][33];
  const int e = e0 + blockIdx.y;
  int b = blockIdx.x;
  const float* in;
  u16* out;
  int R, C, tx, ty;
  if (b < 4096) {
    in = We1 + (size_t)e * 1024 * 4096;
    out = T1 + (size_t)blockIdx.y * tstride;
    R = 1024; C = 4096; tx = b & 127; ty = b >> 7;
  } else {
    b -= 4096;
    in = We2 + (size_t)e * 1024 * 4096;
    out = T2 + (size_t)blockIdx.y * tstride;
    R = 4096; C = 1024; tx = b & 31; ty = b >> 5;
  }
  const int c0 = tx * 32, r0 = ty * 32;
#pragma unroll
  for (int i = 0; i < 4; ++i) {
    int rr = threadIdx.y + i * 8;
    tile[rr][threadIdx.x] = in[(size_t)(r0 + rr) * C + c0 + threadIdx.x];
  }
  __syncthreads();
#pragma unroll
  for (int i = 0; i < 4; ++i) {
    int cc = threadIdx.y + i * 8;
    out[(size_t)(c0 + cc) * R + r0 + threadIdx.x] = f2bf(tile[threadIdx.x][cc]);
  }
}

// ---------------------------------------------------------------------------
// Fused 3-product split-bf16 router GEMM + partial-logits epilogue (as R7).
// ---------------------------------------------------------------------------
__global__ __launch_bounds__(256) void gemm3_router_kernel(
    const u16* __restrict__ Ahi, const u16* __restrict__ Alo,
    const u16* __restrict__ Bhi, const u16* __restrict__ Blo, int K,
    const float* __restrict__ bias, const float* __restrict__ rW2,
    float* __restrict__ parts) {
  __shared__ alignas(16) u16 Sm[4 * 128 * 32];
  __shared__ float pls[2][128][4];
  const int tid = threadIdx.x;
  const int lane = tid & 63;
  const int w = tid >> 6;
  const int wr = w >> 1, wc = w & 1;

  const int flat = blockIdx.x + blockIdx.y * 16;
  const int swz = (flat & 7) * 128 + (flat >> 3);
  const int bxs = swz & 15;
  const int bys = swz >> 4;
  const int brow = bys * 128;
  const int bcol = bxs * 128;

  f32x4 acc[4][4] = {};
  char* S = (char*)Sm;
  const u16* srcs[4] = {Ahi + (size_t)brow * K, Alo + (size_t)brow * K,
                        Bhi + (size_t)bcol * K, Blo + (size_t)bcol * K};
  const int rA = lane & 15;
  const int kg2 = (lane >> 4) * 16;

  const int nk = K >> 5;
  for (int kt = 0; kt < nk; ++kt) {
    const int k0 = kt << 5;
    __syncthreads();
#pragma unroll
    for (int i = 0; i < 8; ++i) {
      int c = tid + 256 * i;
      int tile = c >> 9;
      int cc = c & 511;
      int row = cc >> 2;
      int kp = (cc & 3) << 3;
      gload_lds16(srcs[tile] + (size_t)row * K + (k0 + kp), S + c * 16);
    }
    __syncthreads();

    bf16x8 ah[4], al[4], bh[4], bl[4];
#pragma unroll
    for (int m = 0; m < 4; ++m) {
      int ro = (wr * 64 + m * 16 + rA) * 64 + kg2;
      ah[m] = *(const bf16x8*)(S + ro);
      al[m] = *(const bf16x8*)(S + 8192 + ro);
    }
#pragma unroll
    for (int n = 0; n < 4; ++n) {
      int ro = (wc * 64 + n * 16 + rA) * 64 + kg2;
      bh[n] = *(const bf16x8*)(S + 16384 + ro);
      bl[n] = *(const bf16x8*)(S + 24576 + ro);
    }
#pragma unroll
    for (int m = 0; m < 4; ++m)
#pragma unroll
      for (int n = 0; n < 4; ++n) {
        acc[m][n] = __builtin_amdgcn_mfma_f32_16x16x32_bf16(ah[m], bh[n], acc[m][n], 0, 0, 0);
        acc[m][n] = __builtin_amdgcn_mfma_f32_16x16x32_bf16(al[m], bh[n], acc[m][n], 0, 0, 0);
        acc[m][n] = __builtin_amdgcn_mfma_f32_16x16x32_bf16(ah[m], bl[n], acc[m][n], 0, 0, 0);
      }
  }

  const int cr = (lane >> 4) * 4;
  const int ccx = lane & 15;
  float4 w2v[4];
  float bv[4];
#pragma unroll
  for (int n = 0; n < 4; ++n) {
    const int gc = bcol + wc * 64 + n * 16 + ccx;
    w2v[n] = ((const float4*)rW2)[gc];
    bv[n] = bias[gc];
  }
#pragma unroll
  for (int m = 0; m < 4; ++m) {
    float pl[4][4];
#pragma unroll
    for (int r = 0; r < 4; ++r)
#pragma unroll
      for (int e = 0; e < 4; ++e) pl[r][e] = 0.f;
#pragma unroll
    for (int n = 0; n < 4; ++n)
#pragma unroll
      for (int r = 0; r < 4; ++r) {
        const float v = gelu_f(acc[m][n][r] + bv[n]);
        pl[r][0] += v * w2v[n].x;
        pl[r][1] += v * w2v[n].y;
        pl[r][2] += v * w2v[n].z;
        pl[r][3] += v * w2v[n].w;
      }
#pragma unroll
    for (int off = 8; off; off >>= 1)
#pragma unroll
      for (int r = 0; r < 4; ++r)
#pragma unroll
        for (int e = 0; e < 4; ++e) pl[r][e] += __shfl_xor(pl[r][e], off);
    if ((lane & 15) == 0) {
      const int row = wr * 64 + m * 16 + cr;
#pragma unroll
      for (int r = 0; r < 4; ++r)
#pragma unroll
        for (int e = 0; e < 4; ++e) pls[wc][row + r][e] = pl[r][e];
    }
  }
  __syncthreads();
  for (int i = tid; i < 512; i += 256) {
    const int row = i >> 2, e = i & 3;
    parts[((size_t)bxs * 8192 + brow + row) * 4 + e] =
        pls[0][row][e] + pls[1][row][e];
  }
}

// ---------------------------------------------------------------------------
// topk: deterministic parts reduce + softmax + top-2 + per-expert lists;
// tokslot[t] = (e1*8192+p1, e2*8192+p2) for the combine pass.
// ---------------------------------------------------------------------------
__global__ __launch_bounds__(256) void topk_kernel(
    const float* __restrict__ parts, const float* __restrict__ rb2,
    float* __restrict__ combine, int* __restrict__ cnt, int* __restrict__ list,
    int2* __restrict__ tokslot, int T) {
  const int t = blockIdx.x * 256 + threadIdx.x;
  const int w = threadIdx.x >> 6, lane = threadIdx.x & 63;
  __shared__ int wpre[4][4];
  __shared__ int gbase[4];

  float lg[4] = {rb2[0], rb2[1], rb2[2], rb2[3]};
#pragma unroll
  for (int s = 0; s < 16; ++s) {
    float4 pv = ((const float4*)parts)[(size_t)s * 8192 + t];
    lg[0] += pv.x;
    lg[1] += pv.y;
    lg[2] += pv.z;
    lg[3] += pv.w;
  }
  float mx = fmaxf(fmaxf(lg[0], lg[1]), fmaxf(lg[2], lg[3]));
  float p[4], sum = 0.f;
#pragma unroll
  for (int e = 0; e < 4; ++e) {
    p[e] = expf(lg[e] - mx);
    sum += p[e];
  }
  float inv = 1.0f / sum;
  int i1 = 0;
#pragma unroll
  for (int e = 1; e < 4; ++e)
    if (lg[e] > lg[i1]) i1 = e;
  int i2 = -1;
#pragma unroll
  for (int e = 0; e < 4; ++e)
    if (e != i1 && (i2 < 0 || lg[e] > lg[i2])) i2 = e;
  float4 cw = {0.f, 0.f, 0.f, 0.f};
  ((float*)&cw)[i1] = p[i1] * inv;
  ((float*)&cw)[i2] = p[i2] * inv;
  ((float4*)combine)[t] = cw;

  unsigned long long m[4];
#pragma unroll
  for (int e = 0; e < 4; ++e) m[e] = __ballot(i1 == e || i2 == e);
  if (lane == 0) {
#pragma unroll
    for (int e = 0; e < 4; ++e) wpre[w][e] = (int)__popcll(m[e]);
  }
  __syncthreads();
  if (threadIdx.x < 4) {
    const int e = threadIdx.x;
    int tot = 0;
#pragma unroll
    for (int ww = 0; ww < 4; ++ww) {
      int c = wpre[ww][e];
      wpre[ww][e] = tot;
      tot += c;
    }
    gbase[e] = atomicAdd(&cnt[e], tot);
  }
  __syncthreads();
  const unsigned long long lt = (1ull << lane) - 1ull;
  int p1 = gbase[i1] + wpre[w][i1] + (int)__popcll(m[i1] & lt);
  list[i1 * 8192 + p1] = t;
  int p2 = gbase[i2] + wpre[w][i2] + (int)__popcll(m[i2] & lt);
  list[i2 * 8192 + p2] = t;
  tokslot[t] = make_int2(i1 * 8192 + p1, i2 * 8192 + p2);
}

// ---------------------------------------------------------------------------
// tiny exclusive prefix over cnt[4] -> pre[4]
// ---------------------------------------------------------------------------
__global__ void prefix_kernel(const int* __restrict__ cnt, int* __restrict__ pre) {
  if (threadIdx.x == 0) {
    int s = 0;
#pragma unroll
    for (int e = 0; e < 4; ++e) {
      pre[e] = s;
      s += cnt[e];
    }
  }
}

// ---------------------------------------------------------------------------
// gather-GEMM (expert GEMM-A): R12 single-buffer version. 128x256 tile,
// 8 waves, BK=64, 48KB LDS (2-3 blocks/CU TLP hides L3-resident latency).
// Octet-XOR coalesced staging.  grid (16, 64, nE).
// ---------------------------------------------------------------------------
__global__ __launch_bounds__(512) void gemm_gather_kernel(
    const u16* __restrict__ A, const u16* __restrict__ WT, size_t wts,
    const int* __restrict__ list, const int* __restrict__ cnt_arr,
    const int* __restrict__ hbase_arr, int e0, const float* __restrict__ be1,
    u16* __restrict__ h) {
  const int K = 1024;
  const int e = e0 + blockIdx.z;
  const int cnt = cnt_arr[e];
  const int rb = blockIdx.y;
  if (rb * 128 >= cnt) return;
  const int hbase = hbase_arr[e];
  const int* lst = list + e * 8192;
  const u16* Bt = WT + (size_t)blockIdx.z * wts;
  const float* bias = be1 + e * 4096;

  __shared__ alignas(16) u16 As[128 * 64];   // 16 KB
  __shared__ alignas(16) u16 Bs[256 * 64];   // 32 KB
  const int tid = threadIdx.x;
  const int lane = tid & 63;
  const int w = tid >> 6;
  const int wr = w >> 2, wc = w & 3;
  const int bcol = blockIdx.x * 256;

  const int srow = tid >> 3;
  const int jx8 = (((tid & 7) ^ (srow & 7)) << 3);
  const u16* aS[2];
  const u16* bS[4];
#pragma unroll
  for (int i = 0; i < 2; ++i) {
    int g = rb * 128 + srow + 64 * i;
    int tok = lst[(g < cnt) ? g : rb * 128];
    aS[i] = A + (size_t)tok * K + jx8;
  }
#pragma unroll
  for (int i = 0; i < 4; ++i)
    bS[i] = Bt + (size_t)(bcol + srow + 64 * i) * K + jx8;
  char* AsB = (char*)As;
  char* BsB = (char*)Bs;
  const int dstb = tid * 16;

  f32x4 acc[4][4] = {};
  const int rA = lane & 15;
  const int ksl = lane >> 4;
  const int rx7 = rA & 7;

  const int nk = K >> 6;  // 16
  for (int kt = 0; kt < nk; ++kt) {
    const int kb = kt << 6;
    __syncthreads();
#pragma unroll
    for (int i = 0; i < 2; ++i)
      gload_lds16(aS[i] + kb, AsB + i * 8192 + dstb);
#pragma unroll
    for (int i = 0; i < 4; ++i)
      gload_lds16(bS[i] + kb, BsB + i * 8192 + dstb);
    __syncthreads();
#pragma unroll
    for (int s = 0; s < 2; ++s) {
      bf16x8 a[4], b[4];
      const int sl = (((s * 4 + ksl) ^ rx7) << 4);
#pragma unroll
      for (int m = 0; m < 4; ++m)
        a[m] = *(const bf16x8*)(AsB + (wr * 64 + m * 16 + rA) * 128 + sl);
#pragma unroll
      for (int n = 0; n < 4; ++n)
        b[n] = *(const bf16x8*)(BsB + (wc * 64 + n * 16 + rA) * 128 + sl);
#pragma unroll
      for (int m = 0; m < 4; ++m)
#pragma unroll
        for (int n = 0; n < 4; ++n)
          acc[m][n] =
              __builtin_amdgcn_mfma_f32_16x16x32_bf16(a[m], b[n], acc[m][n], 0, 0, 0);
    }
  }

  const int cr = (lane >> 4) * 4;
  const int ccx = lane & 15;
#pragma unroll
  for (int m = 0; m < 4; ++m)
#pragma unroll
    for (int n = 0; n < 4; ++n) {
      const int gc = bcol + wc * 64 + n * 16 + ccx;
      const float bv = bias[gc];
#pragma unroll
      for (int r = 0; r < 4; ++r) {
        const int gl = rb * 128 + wr * 64 + m * 16 + cr + r;
        if (gl < cnt)
          h[(size_t)(hbase + gl) * 4096 + gc] = f2bf(gelu_fast(acc[m][n][r] + bv));
      }
    }
}

// ---------------------------------------------------------------------------
// scatter-GEMM, ATOMIC-FREE, 128x512 tile + DOUBLE-BUFFER (2x80KB = 160KB
// LDS, the full CU capacity), counted vmcnt(10) + raw s_barrier.  8 waves
// (2Mx4N, wave 64x128), BK=64, K=4096.  grid (2, 64, nE).
// yout[hbase[e]+gl][gc] = bf16(acc + be2[e][gc]).
// ---------------------------------------------------------------------------
__global__ __launch_bounds__(512) void gemm_scatter_y_kernel(
    const u16* __restrict__ h, const int* __restrict__ hbase_arr,
    const u16* __restrict__ WT, size_t wts, const int* __restrict__ cnt_arr,
    int e0, const float* __restrict__ be2, u16* __restrict__ yout) {
  const int K = 4096;
  const int e = e0 + blockIdx.z;
  const int cnt = cnt_arr[e];
  const int rb = blockIdx.y;
  if (rb * 128 >= cnt) return;
  const int hbase = hbase_arr[e];
  const u16* Bt = WT + (size_t)blockIdx.z * wts;
  const float* bias = be2 + e * 1024;

  __shared__ alignas(16) char lds[163840];  // 2 x (A 16KB + B 64KB)
  const int tid = threadIdx.x;
  const int lane = tid & 63;
  const int w = tid >> 6;
  const int wr = w >> 2, wc = w & 3;   // 2M x 4N, wave tile 64 x 128
  const int bcol = blockIdx.x * 512;

  const int srow = tid >> 3;
  const int jx8 = (((tid & 7) ^ (srow & 7)) << 3);
  const u16* aS[2];
  const u16* bS[8];
#pragma unroll
  for (int i = 0; i < 2; ++i)
    aS[i] = h + (size_t)(hbase + rb * 128 + srow + 64 * i) * K + jx8;
#pragma unroll
  for (int i = 0; i < 8; ++i)
    bS[i] = Bt + (size_t)(bcol + srow + 64 * i) * K + jx8;
  const int dstb = tid * 16;

#define S_STAGE(kt, buf)                                                   \
  {                                                                        \
    const int kb_ = (kt) << 6;                                             \
    char* base_ = lds + (buf)*81920;                                       \
    _Pragma("unroll") for (int i = 0; i < 2; ++i)                          \
        gload_lds16(aS[i] + kb_, base_ + i * 8192 + dstb);                 \
    _Pragma("unroll") for (int i = 0; i < 8; ++i)                          \
        gload_lds16(bS[i] + kb_, base_ + 16384 + i * 8192 + dstb);         \
  }

  f32x4 acc[4][8] = {};
  const int rA = lane & 15;
  const int ksl = lane >> 4;
  const int rx7 = rA & 7;

  const int nk = K >> 6;  // 64
  int cur = 0;
  S_STAGE(0, 0);
  for (int kt = 0; kt < nk; ++kt) {
    if (kt + 1 < nk) {
      S_STAGE(kt + 1, cur ^ 1);
      asm volatile("s_waitcnt vmcnt(10)" ::: "memory");
    } else {
      asm volatile("s_waitcnt vmcnt(0)" ::: "memory");
    }
    __builtin_amdgcn_s_barrier();
    const char* Ab_ = lds + cur * 81920;
    const char* Bb_ = Ab_ + 16384;
#pragma unroll
    for (int s = 0; s < 2; ++s) {
      bf16x8 a[4], b[8];
      const int sl = (((s * 4 + ksl) ^ rx7) << 4);
#pragma unroll
      for (int m = 0; m < 4; ++m)
        a[m] = *(const bf16x8*)(Ab_ + (wr * 64 + m * 16 + rA) * 128 + sl);
#pragma unroll
      for (int n = 0; n < 8; ++n)
        b[n] = *(const bf16x8*)(Bb_ + (wc * 128 + n * 16 + rA) * 128 + sl);
#pragma unroll
      for (int m = 0; m < 4; ++m)
#pragma unroll
        for (int n = 0; n < 8; ++n)
          acc[m][n] =
              __builtin_amdgcn_mfma_f32_16x16x32_bf16(a[m], b[n], acc[m][n], 0, 0, 0);
    }
    __builtin_amdgcn_s_barrier();
    cur ^= 1;
  }
#undef S_STAGE

  const int cr = (lane >> 4) * 4;
  const int ccx = lane & 15;
#pragma unroll
  for (int m = 0; m < 4; ++m)
#pragma unroll
    for (int r = 0; r < 4; ++r) {
      const int gl = rb * 128 + wr * 64 + m * 16 + cr + r;
      if (gl >= cnt) continue;
      u16* yrow = yout + (size_t)(hbase + gl) * 1024;
#pragma unroll
      for (int n = 0; n < 8; ++n) {
        const int gc = bcol + wc * 128 + n * 16 + ccx;
        yrow[gc] = f2bf(acc[m][n][r] + bias[gc]);
      }
    }
}

// ---------------------------------------------------------------------------
// combine: out[t] = g1*yout[r1] + g2*yout[r2] (yout bf16); r = prefix[e]+pos.
// ---------------------------------------------------------------------------
__global__ __launch_bounds__(256) void combine_kernel(
    const u16* __restrict__ yout, const int2* __restrict__ tokslot,
    const int* __restrict__ prefix, const float* __restrict__ gates,
    float* __restrict__ out) {
  const int w = threadIdx.x >> 6, lane = threadIdx.x & 63;
  const int t = blockIdx.x * 4 + w;
  const int2 s = tokslot[t];
  const int e1 = s.x >> 13, p1 = s.x & 8191;
  const int e2 = s.y >> 13, p2 = s.y & 8191;
  const int r1 = prefix[e1] + p1;
  const int r2 = prefix[e2] + p2;
  const float g1 = gates[(size_t)t * 4 + e1];
  const float g2 = gates[(size_t)t * 4 + e2];
  const ushort4* y1 = (const ushort4*)(yout + (size_t)r1 * 1024);
  const ushort4* y2 = (const ushort4*)(yout + (size_t)r2 * 1024);
  float4* o = (float4*)(out + (size_t)t * 1024);
#pragma unroll
  for (int j = 0; j < 4; ++j) {
    const int c = lane + j * 64;
    ushort4 a = y1[c], b = y2[c];
    float4 r;
    r.x = g1 * bf2f(a.x) + g2 * bf2f(b.x);
    r.y = g1 * bf2f(a.y) + g2 * bf2f(b.y);
    r.z = g1 * bf2f(a.z) + g2 * bf2f(b.z);
    r.w = g1 * bf2f(a.w) + g2 * bf2f(b.w);
    o[c] = r;
  }
}

// ---------------------------------------------------------------------------
// FALLBACK scatter (atomic, split-K x2) — single-buffered R10 version.
// ---------------------------------------------------------------------------
__global__ __launch_bounds__(512) void gemm_scatter_kernel(
    const u16* __restrict__ h, const int* __restrict__ hbase_arr,
    const u16* __restrict__ WT, size_t wts, const int* __restrict__ list,
    const int* __restrict__ cnt_arr, int e0, const float* __restrict__ be2,
    const float* __restrict__ combine, float* __restrict__ out) {
  const int K = 4096;
  const int zslot = blockIdx.z >> 1;
  const int kz = blockIdx.z & 1;
  const int e = e0 + zslot;
  const int cnt = cnt_arr[e];
  const int rb = blockIdx.y;
  if (rb * 128 >= cnt) return;
  const int hbase = hbase_arr[e];
  const int* lst = list + e * 8192;
  const u16* Bt = WT + (size_t)zslot * wts;
  const float* bias = be2 + e * 1024;
  const int koff = kz * 2048;

  __shared__ alignas(16) u16 As[128 * 64];
  __shared__ alignas(16) u16 Bs[256 * 64];
  const int tid = threadIdx.x;
  const int lane = tid & 63;
  const int w = tid >> 6;
  const int wr = w >> 2, wc = w & 3;
  const int bcol = blockIdx.x * 256;

  const int srow = tid >> 3;
  const int jx8 = (((tid & 7) ^ (srow & 7)) << 3);
  const u16* aS[2];
  const u16* bS[4];
#pragma unroll
  for (int i = 0; i < 2; ++i)
    aS[i] = h + (size_t)(hbase + rb * 128 + srow + 64 * i) * K + koff + jx8;
#pragma unroll
  for (int i = 0; i < 4; ++i)
    bS[i] = Bt + (size_t)(bcol + srow + 64 * i) * K + koff + jx8;
  char* AsB = (char*)As;
  char* BsB = (char*)Bs;
  const int dstb = tid * 16;

  f32x4 acc[4][4] = {};
  const int rA = lane & 15;
  const int ksl = lane >> 4;
  const int rx7 = rA & 7;

  const int nk = 2048 >> 6;
  for (int kt = 0; kt < nk; ++kt) {
    const int kb = kt << 6;
    __syncthreads();
#pragma unroll
    for (int i = 0; i < 2; ++i)
      gload_lds16(aS[i] + kb, AsB + i * 8192 + dstb);
#pragma unroll
    for (int i = 0; i < 4; ++i)
      gload_lds16(bS[i] + kb, BsB + i * 8192 + dstb);
    __syncthreads();
#pragma unroll
    for (int s = 0; s < 2; ++s) {
      bf16x8 a[4], b[4];
      const int sl = (((s * 4 + ksl) ^ rx7) << 4);
#pragma unroll
      for (int m = 0; m < 4; ++m)
        a[m] = *(const bf16x8*)(AsB + (wr * 64 + m * 16 + rA) * 128 + sl);
#pragma unroll
      for (int n = 0; n < 4; ++n)
        b[n] = *(const bf16x8*)(BsB + (wc * 64 + n * 16 + rA) * 128 + sl);
#pragma unroll
      for (int m = 0; m < 4; ++m)
#pragma unroll
        for (int n = 0; n < 4; ++n)
          acc[m][n] =
              __builtin_amdgcn_mfma_f32_16x16x32_bf16(a[m], b[n], acc[m][n], 0, 0, 0);
    }
  }

  const int cr = (lane >> 4) * 4;
  const int ccx = lane & 15;
  const bool addb = (kz == 0);
#pragma unroll
  for (int m = 0; m < 4; ++m)
#pragma unroll
    for (int r = 0; r < 4; ++r) {
      const int gl = rb * 128 + wr * 64 + m * 16 + cr + r;
      if (gl >= cnt) continue;
      const int tok = lst[gl];
      const float gcoef = combine[(size_t)tok * 4 + e];
      float* orow = out + (size_t)tok * 1024;
#pragma unroll
      for (int n = 0; n < 4; ++n) {
        const int gc = bcol + wc * 64 + n * 16 + ccx;
        float v = acc[m][n][r];
        if (addb) v += bias[gc];
        atomicAdd(&orow[gc], gcoef * v);
      }
    }
}

// ---------------------------------------------------------------------------
extern "C" void kernel_launch(void* const* d_in, const int* in_sizes, int n_in,
                              void* d_out, int out_size, void* d_ws,
                              size_t ws_size, hipStream_t stream) {
  const float* x = (const float*)d_in[0];
  const float* rW1 = (const float*)d_in[1];
  const float* rb1 = (const float*)d_in[2];
  const float* rW2 = (const float*)d_in[3];
  const float* rb2 = (const float*)d_in[4];
  const float* We1 = (const float*)d_in[5];
  const float* be1 = (const float*)d_in[6];
  const float* We2 = (const float*)d_in[7];
  const float* be2 = (const float*)d_in[8];
  float* out = (float*)d_out;

  const int T = 8192, D = 1024, D2 = 2048, H = 4096, E = 4;
  const size_t WTS = (size_t)H * D;

  char* ws = (char*)d_ws;
  size_t off = 0;
  auto alloc = [&](size_t bytes) {
    char* p = ws + off;
    off = (off + bytes + 255) & ~(size_t)255;
    return p;
  };
  u16* x_hi = (u16*)alloc((size_t)T * D * 2);            // 16 MB
  float* combine = (float*)alloc((size_t)T * 4 * 4);
  int* cnt = (int*)alloc(256);
  int* prefix = cnt + 4;
  int* list = (int*)alloc((size_t)4 * 8192 * 4);
  int2* tokslot = (int2*)alloc((size_t)T * 8);           // 64 KB
  const size_t common_off = off;

  bool merged;
  u16 *We1T, *We2T, *h, *x_lo, *rW1T_hi, *rW1T_lo, *yout;
  float* parts;
  {
    size_t o = common_off;
    auto a2 = [&](size_t bytes) {
      char* p = ws + o;
      o = (o + bytes + 255) & ~(size_t)255;
      return p;
    };
    u16* w1 = (u16*)a2((size_t)4 * WTS * 2);             // 32 MB
    u16* w2 = (u16*)a2((size_t)4 * WTS * 2);             // 32 MB
    char* hreg = a2((size_t)16384 * H * 2 + (2u << 20)); // 128 MB + 2 MB pad
    merged = (o <= ws_size);  // ~211 MB total — fits (R8-R15)
    if (merged) {
      We1T = w1;
      We2T = w2;
      h = (u16*)hreg;
      yout = w1;  // ALIAS: We1T dead after gather-all; yout = 32 MB bf16
      x_lo = (u16*)hreg;                        // 16 MB (dead before h)
      rW1T_hi = (u16*)(hreg + (16u << 20));     // 4 MB
      rW1T_lo = (u16*)(hreg + (20u << 20));     // 4 MB
      parts = (float*)(hreg + (24u << 20));     // 2 MB
    }
  }
  if (!merged) {
    off = common_off;
    We1T = (u16*)alloc(WTS * 2);
    We2T = (u16*)alloc(WTS * 2);
    x_lo = (u16*)alloc((size_t)T * D * 2);
    rW1T_hi = (u16*)alloc((size_t)D2 * D * 2);
    rW1T_lo = (u16*)alloc((size_t)D2 * D * 2);
    parts = (float*)alloc((size_t)16 * T * 4 * 4);
    h = (u16*)alloc((size_t)T * H * 2);
    yout = nullptr;
  }

  hipMemsetAsync(cnt, 0, 32, stream);
  if (!merged) hipMemsetAsync(out, 0, (size_t)T * D * 4, stream);

  dim3 tb(32, 8);

  convert_split_kernel<<<2048, 256, 0, stream>>>(x, x_hi, x_lo, T * D / 4);
  transpose_split_kernel<<<dim3(D2 / 32, D / 32), tb, 0, stream>>>(
      rW1, rW1T_hi, rW1T_lo, D, D2);
  gemm3_router_kernel<<<dim3(16, 64), 256, 0, stream>>>(
      x_hi, x_lo, rW1T_hi, rW1T_lo, D, rb1, rW2, parts);
  topk_kernel<<<T / 256, 256, 0, stream>>>(parts, rb2, combine, cnt, list,
                                           tokslot, T);

  if (merged) {
    prefix_kernel<<<1, 64, 0, stream>>>(cnt, prefix);
    transpose_pair_kernel<<<dim3(8192, 4), tb, 0, stream>>>(
        We1, We2, We1T, We2T, WTS, 0);
    gemm_gather_kernel<<<dim3(16, 64, 4), 512, 0, stream>>>(
        x_hi, We1T, WTS, list, cnt, prefix, 0, be1, h);
    // yout aliases We1T (dead now); scatter: 128x512 + dbuf (160KB LDS)
    gemm_scatter_y_kernel<<<dim3(2, 64, 4), 512, 0, stream>>>(
        h, prefix, We2T, WTS, cnt, 0, be2, yout);
    combine_kernel<<<T / 4, 256, 0, stream>>>(yout, tokslot, prefix, combine,
                                              out);
  } else {
    for (int e = 0; e < E; ++e) {
      transpose_pair_kernel<<<dim3(8192, 1), tb, 0, stream>>>(
          We1, We2, We1T, We2T, 0, e);
      gemm_gather_kernel<<<dim3(16, 64, 1), 512, 0, stream>>>(
          x_hi, We1T, 0, list, cnt, prefix /*zeros*/, e, be1, h);
      gemm_scatter_kernel<<<dim3(4, 64, 2), 512, 0, stream>>>(
          h, prefix /*zeros*/, We2T, 0, list, cnt, e, be2, combine, out);
    }
  }
}

// Round 17
// 573.449 us; speedup vs baseline: 1.1756x; 1.0834x over previous
//
#include <hip/hip_runtime.h>
#include <math.h>

// ---------------------------------------------------------------------------
// CoLT5 MoE layer, round 17 (base = round 14, 586us; R15/R16 tile experiments
// reverted):
//  - scatter_y: PROVEN R12 body (128x256, single-buf 48KB, 2 blk/CU) with an
//    XCD-pair dispatch remap: the 4 column-blocks sharing one h-row-panel get
//    the same flat%8 (same XCD under round-robin) -> panel fetched ~once per
//    XCD instead of 4x.  pair = (flat&7)+8*(flat>>5), bx = (flat>>3)&3;
//    active pairs uniform mod 8 -> balanced early-exit.
//  - gather: unchanged R12 single-buffer (proven).
//  - rest identical (atomic-free scatter, bf16 yout aliasing We1T, ~211MB
//    merged layout, R10 atomic fallback).
// Shapes hard-coded: T=8192, D=1024, D2=2048, H=4096, E=4.
// ---------------------------------------------------------------------------

typedef short bf16x8 __attribute__((ext_vector_type(8)));
typedef float f32x4 __attribute__((ext_vector_type(4)));
typedef unsigned short u16;

__device__ __forceinline__ u16 f2bf(float f) {
  unsigned u = __float_as_uint(f);
  u += 0x7FFFu + ((u >> 16) & 1u);  // round-to-nearest-even
  return (u16)(u >> 16);
}
__device__ __forceinline__ float bf2f(u16 s) {
  return __uint_as_float(((unsigned)s) << 16);
}
// exact gelu (router path: logit precision decides top-2 ordering)
__device__ __forceinline__ float gelu_f(float x) {
  return 0.5f * x * (1.0f + erff(x * 0.70710678118654752f));
}
// fast gelu (expert path; |err|<=3e-3 << 0.119 threshold)
__device__ __forceinline__ float gelu_fast(float x) {
  float y = 1.5957691216057308f * (x + 0.044715f * x * x * x);
  float e = __expf(y);
  float t = 1.0f - 2.0f * __builtin_amdgcn_rcpf(e + 1.0f);
  return 0.5f * x * (1.0f + t);
}
__device__ __forceinline__ void gload_lds16(const void* g, void* l) {
  __builtin_amdgcn_global_load_lds(
      (const __attribute__((address_space(1))) void*)g,
      (__attribute__((address_space(3))) void*)l, 16, 0, 0);
}

// ---------------------------------------------------------------------------
// x (fp32) -> x_hi (bf16) + x_lo (bf16 residual)
// ---------------------------------------------------------------------------
__global__ __launch_bounds__(256) void convert_split_kernel(
    const float* __restrict__ in, u16* __restrict__ hi, u16* __restrict__ lo,
    int n4) {
  int i = blockIdx.x * blockDim.x + threadIdx.x;
  int stride = gridDim.x * blockDim.x;
  for (; i < n4; i += stride) {
    float4 v = ((const float4*)in)[i];
    float f[4] = {v.x, v.y, v.z, v.w};
    ushort4 h4, l4;
    u16* hp = (u16*)&h4;
    u16* lp = (u16*)&l4;
#pragma unroll
    for (int u = 0; u < 4; ++u) {
      u16 h = f2bf(f[u]);
      hp[u] = h;
      lp[u] = f2bf(f[u] - bf2f(h));
    }
    ((ushort4*)hi)[i] = h4;
    ((ushort4*)lo)[i] = l4;
  }
}

// ---------------------------------------------------------------------------
// transpose fp32 [R][C] -> bf16 [C][R] hi + lo residual (for rW1)
// ---------------------------------------------------------------------------
__global__ __launch_bounds__(256) void transpose_split_kernel(
    const float* __restrict__ in, u16* __restrict__ hi, u16* __restrict__ lo,
    int R, int C) {
  __shared__ float tile[32][33];
  const int c0 = blockIdx.x * 32, r0 = blockIdx.y * 32;
#pragma unroll
  for (int i = 0; i < 4; ++i) {
    int rr = threadIdx.y + i * 8;
    tile[rr][threadIdx.x] = in[(size_t)(r0 + rr) * C + c0 + threadIdx.x];
  }
  __syncthreads();
#pragma unroll
  for (int i = 0; i < 4; ++i) {
    int cc = threadIdx.y + i * 8;
    float v = tile[threadIdx.x][cc];
    u16 h = f2bf(v);
    size_t oidx = (size_t)(c0 + cc) * R + r0 + threadIdx.x;
    hi[oidx] = h;
    lo[oidx] = f2bf(v - bf2f(h));
  }
}

// ---------------------------------------------------------------------------
// expert-weight transpose pair; grid (8192, nE), y = expert slot.
// ---------------------------------------------------------------------------
__global__ __launch_bounds__(256) void transpose_pair_kernel(
    const float* __restrict__ We1, const float* __restrict__ We2,
    u16* __restrict__ T1, u16* __restrict__ T2, size_t tstride, int e0) {
  __shared__ float tile[32][33];
  const int e = e0 + blockIdx.y;
  int b = blockIdx.x;
  const float* in;
  u16* out;
  int R, C, tx, ty;
  if (b < 4096) {
    in = We1 + (size_t)e * 1024 * 4096;
    out = T1 + (size_t)blockIdx.y * tstride;
    R = 1024; C = 4096; tx = b & 127; ty = b >> 7;
  } else {
    b -= 4096;
    in = We2 + (size_t)e * 1024 * 4096;
    out = T2 + (size_t)blockIdx.y * tstride;
    R = 4096; C = 1024; tx = b & 31; ty = b >> 5;
  }
  const int c0 = tx * 32, r0 = ty * 32;
#pragma unroll
  for (int i = 0; i < 4; ++i) {
    int rr = threadIdx.y + i * 8;
    tile[rr][threadIdx.x] = in[(size_t)(r0 + rr) * C + c0 + threadIdx.x];
  }
  __syncthreads();
#pragma unroll
  for (int i = 0; i < 4; ++i) {
    int cc = threadIdx.y + i * 8;
    out[(size_t)(c0 + cc) * R + r0 + threadIdx.x] = f2bf(tile[threadIdx.x][cc]);
  }
}

// ---------------------------------------------------------------------------
// Fused 3-product split-bf16 router GEMM + partial-logits epilogue (as R7).
// ---------------------------------------------------------------------------
__global__ __launch_bounds__(256) void gemm3_router_kernel(
    const u16* __restrict__ Ahi, const u16* __restrict__ Alo,
    const u16* __restrict__ Bhi, const u16* __restrict__ Blo, int K,
    const float* __restrict__ bias, const float* __restrict__ rW2,
    float* __restrict__ parts) {
  __shared__ alignas(16) u16 Sm[4 * 128 * 32];
  __shared__ float pls[2][128][4];
  const int tid = threadIdx.x;
  const int lane = tid & 63;
  const int w = tid >> 6;
  const int wr = w >> 1, wc = w & 1;

  const int flat = blockIdx.x + blockIdx.y * 16;
  const int swz = (flat & 7) * 128 + (flat >> 3);
  const int bxs = swz & 15;
  const int bys = swz >> 4;
  const int brow = bys * 128;
  const int bcol = bxs * 128;

  f32x4 acc[4][4] = {};
  char* S = (char*)Sm;
  const u16* srcs[4] = {Ahi + (size_t)brow * K, Alo + (size_t)brow * K,
                        Bhi + (size_t)bcol * K, Blo + (size_t)bcol * K};
  const int rA = lane & 15;
  const int kg2 = (lane >> 4) * 16;

  const int nk = K >> 5;
  for (int kt = 0; kt < nk; ++kt) {
    const int k0 = kt << 5;
    __syncthreads();
#pragma unroll
    for (int i = 0; i < 8; ++i) {
      int c = tid + 256 * i;
      int tile = c >> 9;
      int cc = c & 511;
      int row = cc >> 2;
      int kp = (cc & 3) << 3;
      gload_lds16(srcs[tile] + (size_t)row * K + (k0 + kp), S + c * 16);
    }
    __syncthreads();

    bf16x8 ah[4], al[4], bh[4], bl[4];
#pragma unroll
    for (int m = 0; m < 4; ++m) {
      int ro = (wr * 64 + m * 16 + rA) * 64 + kg2;
      ah[m] = *(const bf16x8*)(S + ro);
      al[m] = *(const bf16x8*)(S + 8192 + ro);
    }
#pragma unroll
    for (int n = 0; n < 4; ++n) {
      int ro = (wc * 64 + n * 16 + rA) * 64 + kg2;
      bh[n] = *(const bf16x8*)(S + 16384 + ro);
      bl[n] = *(const bf16x8*)(S + 24576 + ro);
    }
#pragma unroll
    for (int m = 0; m < 4; ++m)
#pragma unroll
      for (int n = 0; n < 4; ++n) {
        acc[m][n] = __builtin_amdgcn_mfma_f32_16x16x32_bf16(ah[m], bh[n], acc[m][n], 0, 0, 0);
        acc[m][n] = __builtin_amdgcn_mfma_f32_16x16x32_bf16(al[m], bh[n], acc[m][n], 0, 0, 0);
        acc[m][n] = __builtin_amdgcn_mfma_f32_16x16x32_bf16(ah[m], bl[n], acc[m][n], 0, 0, 0);
      }
  }

  const int cr = (lane >> 4) * 4;
  const int ccx = lane & 15;
  float4 w2v[4];
  float bv[4];
#pragma unroll
  for (int n = 0; n < 4; ++n) {
    const int gc = bcol + wc * 64 + n * 16 + ccx;
    w2v[n] = ((const float4*)rW2)[gc];
    bv[n] = bias[gc];
  }
#pragma unroll
  for (int m = 0; m < 4; ++m) {
    float pl[4][4];
#pragma unroll
    for (int r = 0; r < 4; ++r)
#pragma unroll
      for (int e = 0; e < 4; ++e) pl[r][e] = 0.f;
#pragma unroll
    for (int n = 0; n < 4; ++n)
#pragma unroll
      for (int r = 0; r < 4; ++r) {
        const float v = gelu_f(acc[m][n][r] + bv[n]);
        pl[r][0] += v * w2v[n].x;
        pl[r][1] += v * w2v[n].y;
        pl[r][2] += v * w2v[n].z;
        pl[r][3] += v * w2v[n].w;
      }
#pragma unroll
    for (int off = 8; off; off >>= 1)
#pragma unroll
      for (int r = 0; r < 4; ++r)
#pragma unroll
        for (int e = 0; e < 4; ++e) pl[r][e] += __shfl_xor(pl[r][e], off);
    if ((lane & 15) == 0) {
      const int row = wr * 64 + m * 16 + cr;
#pragma unroll
      for (int r = 0; r < 4; ++r)
#pragma unroll
        for (int e = 0; e < 4; ++e) pls[wc][row + r][e] = pl[r][e];
    }
  }
  __syncthreads();
  for (int i = tid; i < 512; i += 256) {
    const int row = i >> 2, e = i & 3;
    parts[((size_t)bxs * 8192 + brow + row) * 4 + e] =
        pls[0][row][e] + pls[1][row][e];
  }
}

// ---------------------------------------------------------------------------
// topk: deterministic parts reduce + softmax + top-2 + per-expert lists;
// tokslot[t] = (e1*8192+p1, e2*8192+p2) for the combine pass.
// ---------------------------------------------------------------------------
__global__ __launch_bounds__(256) void topk_kernel(
    const float* __restrict__ parts, const float* __restrict__ rb2,
    float* __restrict__ combine, int* __restrict__ cnt, int* __restrict__ list,
    int2* __restrict__ tokslot, int T) {
  const int t = blockIdx.x * 256 + threadIdx.x;
  const int w = threadIdx.x >> 6, lane = threadIdx.x & 63;
  __shared__ int wpre[4][4];
  __shared__ int gbase[4];

  float lg[4] = {rb2[0], rb2[1], rb2[2], rb2[3]};
#pragma unroll
  for (int s = 0; s < 16; ++s) {
    float4 pv = ((const float4*)parts)[(size_t)s * 8192 + t];
    lg[0] += pv.x;
    lg[1] += pv.y;
    lg[2] += pv.z;
    lg[3] += pv.w;
  }
  float mx = fmaxf(fmaxf(lg[0], lg[1]), fmaxf(lg[2], lg[3]));
  float p[4], sum = 0.f;
#pragma unroll
  for (int e = 0; e < 4; ++e) {
    p[e] = expf(lg[e] - mx);
    sum += p[e];
  }
  float inv = 1.0f / sum;
  int i1 = 0;
#pragma unroll
  for (int e = 1; e < 4; ++e)
    if (lg[e] > lg[i1]) i1 = e;
  int i2 = -1;
#pragma unroll
  for (int e = 0; e < 4; ++e)
    if (e != i1 && (i2 < 0 || lg[e] > lg[i2])) i2 = e;
  float4 cw = {0.f, 0.f, 0.f, 0.f};
  ((float*)&cw)[i1] = p[i1] * inv;
  ((float*)&cw)[i2] = p[i2] * inv;
  ((float4*)combine)[t] = cw;

  unsigned long long m[4];
#pragma unroll
  for (int e = 0; e < 4; ++e) m[e] = __ballot(i1 == e || i2 == e);
  if (lane == 0) {
#pragma unroll
    for (int e = 0; e < 4; ++e) wpre[w][e] = (int)__popcll(m[e]);
  }
  __syncthreads();
  if (threadIdx.x < 4) {
    const int e = threadIdx.x;
    int tot = 0;
#pragma unroll
    for (int ww = 0; ww < 4; ++ww) {
      int c = wpre[ww][e];
      wpre[ww][e] = tot;
      tot += c;
    }
    gbase[e] = atomicAdd(&cnt[e], tot);
  }
  __syncthreads();
  const unsigned long long lt = (1ull << lane) - 1ull;
  int p1 = gbase[i1] + wpre[w][i1] + (int)__popcll(m[i1] & lt);
  list[i1 * 8192 + p1] = t;
  int p2 = gbase[i2] + wpre[w][i2] + (int)__popcll(m[i2] & lt);
  list[i2 * 8192 + p2] = t;
  tokslot[t] = make_int2(i1 * 8192 + p1, i2 * 8192 + p2);
}

// ---------------------------------------------------------------------------
// tiny exclusive prefix over cnt[4] -> pre[4]
// ---------------------------------------------------------------------------
__global__ void prefix_kernel(const int* __restrict__ cnt, int* __restrict__ pre) {
  if (threadIdx.x == 0) {
    int s = 0;
#pragma unroll
    for (int e = 0; e < 4; ++e) {
      pre[e] = s;
      s += cnt[e];
    }
  }
}

// ---------------------------------------------------------------------------
// gather-GEMM (expert GEMM-A): R12 single-buffer version. 128x256 tile,
// 8 waves, BK=64, 48KB LDS (2-3 blocks/CU TLP hides L3-resident latency).
// Octet-XOR coalesced staging.  grid (16, 64, nE).
// ---------------------------------------------------------------------------
__global__ __launch_bounds__(512) void gemm_gather_kernel(
    const u16* __restrict__ A, const u16* __restrict__ WT, size_t wts,
    const int* __restrict__ list, const int* __restrict__ cnt_arr,
    const int* __restrict__ hbase_arr, int e0, const float* __restrict__ be1,
    u16* __restrict__ h) {
  const int K = 1024;
  const int e = e0 + blockIdx.z;
  const int cnt = cnt_arr[e];
  const int rb = blockIdx.y;
  if (rb * 128 >= cnt) return;
  const int hbase = hbase_arr[e];
  const int* lst = list + e * 8192;
  const u16* Bt = WT + (size_t)blockIdx.z * wts;
  const float* bias = be1 + e * 4096;

  __shared__ alignas(16) u16 As[128 * 64];   // 16 KB
  __shared__ alignas(16) u16 Bs[256 * 64];   // 32 KB
  const int tid = threadIdx.x;
  const int lane = tid & 63;
  const int w = tid >> 6;
  const int wr = w >> 2, wc = w & 3;
  const int bcol = blockIdx.x * 256;

  const int srow = tid >> 3;
  const int jx8 = (((tid & 7) ^ (srow & 7)) << 3);
  const u16* aS[2];
  const u16* bS[4];
#pragma unroll
  for (int i = 0; i < 2; ++i) {
    int g = rb * 128 + srow + 64 * i;
    int tok = lst[(g < cnt) ? g : rb * 128];
    aS[i] = A + (size_t)tok * K + jx8;
  }
#pragma unroll
  for (int i = 0; i < 4; ++i)
    bS[i] = Bt + (size_t)(bcol + srow + 64 * i) * K + jx8;
  char* AsB = (char*)As;
  char* BsB = (char*)Bs;
  const int dstb = tid * 16;

  f32x4 acc[4][4] = {};
  const int rA = lane & 15;
  const int ksl = lane >> 4;
  const int rx7 = rA & 7;

  const int nk = K >> 6;  // 16
  for (int kt = 0; kt < nk; ++kt) {
    const int kb = kt << 6;
    __syncthreads();
#pragma unroll
    for (int i = 0; i < 2; ++i)
      gload_lds16(aS[i] + kb, AsB + i * 8192 + dstb);
#pragma unroll
    for (int i = 0; i < 4; ++i)
      gload_lds16(bS[i] + kb, BsB + i * 8192 + dstb);
    __syncthreads();
#pragma unroll
    for (int s = 0; s < 2; ++s) {
      bf16x8 a[4], b[4];
      const int sl = (((s * 4 + ksl) ^ rx7) << 4);
#pragma unroll
      for (int m = 0; m < 4; ++m)
        a[m] = *(const bf16x8*)(AsB + (wr * 64 + m * 16 + rA) * 128 + sl);
#pragma unroll
      for (int n = 0; n < 4; ++n)
        b[n] = *(const bf16x8*)(BsB + (wc * 64 + n * 16 + rA) * 128 + sl);
#pragma unroll
      for (int m = 0; m < 4; ++m)
#pragma unroll
        for (int n = 0; n < 4; ++n)
          acc[m][n] =
              __builtin_amdgcn_mfma_f32_16x16x32_bf16(a[m], b[n], acc[m][n], 0, 0, 0);
    }
  }

  const int cr = (lane >> 4) * 4;
  const int ccx = lane & 15;
#pragma unroll
  for (int m = 0; m < 4; ++m)
#pragma unroll
    for (int n = 0; n < 4; ++n) {
      const int gc = bcol + wc * 64 + n * 16 + ccx;
      const float bv = bias[gc];
#pragma unroll
      for (int r = 0; r < 4; ++r) {
        const int gl = rb * 128 + wr * 64 + m * 16 + cr + r;
        if (gl < cnt)
          h[(size_t)(hbase + gl) * 4096 + gc] = f2bf(gelu_fast(acc[m][n][r] + bv));
      }
    }
}

// ---------------------------------------------------------------------------
// scatter-GEMM, ATOMIC-FREE (R12 proven body, XCD-pair dispatch remap):
// 128x256 tile, 8 waves, BK=64, 48KB LDS, K=4096.  grid 1024 (1D).
// The 4 bx-blocks of a (rb,e) pair share flat%8 -> same XCD -> shared L2
// h-panel.  pair = (flat&7)+8*(flat>>5); bx = (flat>>3)&3.
// yout[hbase[e]+gl][gc] = bf16(acc + be2[e][gc]).
// ---------------------------------------------------------------------------
__global__ __launch_bounds__(512) void gemm_scatter_y_kernel(
    const u16* __restrict__ h, const int* __restrict__ hbase_arr,
    const u16* __restrict__ WT, size_t wts, const int* __restrict__ cnt_arr,
    int e0, const float* __restrict__ be2, u16* __restrict__ yout) {
  const int K = 4096;
  const int flat = blockIdx.x;
  const int pair = (flat & 7) + ((flat >> 5) << 3);   // [0,256)
  const int bxi = (flat >> 3) & 3;
  const int ez = pair >> 6;                            // expert slot
  const int rb = pair & 63;
  const int e = e0 + ez;
  const int cnt = cnt_arr[e];
  if (rb * 128 >= cnt) return;
  const int hbase = hbase_arr[e];
  const u16* Bt = WT + (size_t)ez * wts;
  const float* bias = be2 + e * 1024;

  __shared__ alignas(16) u16 As[128 * 64];
  __shared__ alignas(16) u16 Bs[256 * 64];
  const int tid = threadIdx.x;
  const int lane = tid & 63;
  const int w = tid >> 6;
  const int wr = w >> 2, wc = w & 3;
  const int bcol = bxi * 256;

  const int srow = tid >> 3;
  const int jx8 = (((tid & 7) ^ (srow & 7)) << 3);
  const u16* aS[2];
  const u16* bS[4];
#pragma unroll
  for (int i = 0; i < 2; ++i)
    aS[i] = h + (size_t)(hbase + rb * 128 + srow + 64 * i) * K + jx8;
#pragma unroll
  for (int i = 0; i < 4; ++i)
    bS[i] = Bt + (size_t)(bcol + srow + 64 * i) * K + jx8;
  char* AsB = (char*)As;
  char* BsB = (char*)Bs;
  const int dstb = tid * 16;

  f32x4 acc[4][4] = {};
  const int rA = lane & 15;
  const int ksl = lane >> 4;
  const int rx7 = rA & 7;

  const int nk = K >> 6;  // 64
  for (int kt = 0; kt < nk; ++kt) {
    const int kb = kt << 6;
    __syncthreads();
#pragma unroll
    for (int i = 0; i < 2; ++i)
      gload_lds16(aS[i] + kb, AsB + i * 8192 + dstb);
#pragma unroll
    for (int i = 0; i < 4; ++i)
      gload_lds16(bS[i] + kb, BsB + i * 8192 + dstb);
    __syncthreads();
#pragma unroll
    for (int s = 0; s < 2; ++s) {
      bf16x8 a[4], b[4];
      const int sl = (((s * 4 + ksl) ^ rx7) << 4);
#pragma unroll
      for (int m = 0; m < 4; ++m)
        a[m] = *(const bf16x8*)(AsB + (wr * 64 + m * 16 + rA) * 128 + sl);
#pragma unroll
      for (int n = 0; n < 4; ++n)
        b[n] = *(const bf16x8*)(BsB + (wc * 64 + n * 16 + rA) * 128 + sl);
#pragma unroll
      for (int m = 0; m < 4; ++m)
#pragma unroll
        for (int n = 0; n < 4; ++n)
          acc[m][n] =
              __builtin_amdgcn_mfma_f32_16x16x32_bf16(a[m], b[n], acc[m][n], 0, 0, 0);
    }
  }

  const int cr = (lane >> 4) * 4;
  const int ccx = lane & 15;
#pragma unroll
  for (int m = 0; m < 4; ++m)
#pragma unroll
    for (int r = 0; r < 4; ++r) {
      const int gl = rb * 128 + wr * 64 + m * 16 + cr + r;
      if (gl >= cnt) continue;
      u16* yrow = yout + (size_t)(hbase + gl) * 1024;
#pragma unroll
      for (int n = 0; n < 4; ++n) {
        const int gc = bcol + wc * 64 + n * 16 + ccx;
        yrow[gc] = f2bf(acc[m][n][r] + bias[gc]);
      }
    }
}

// ---------------------------------------------------------------------------
// combine: out[t] = g1*yout[r1] + g2*yout[r2] (yout bf16); r = prefix[e]+pos.
// ---------------------------------------------------------------------------
__global__ __launch_bounds__(256) void combine_kernel(
    const u16* __restrict__ yout, const int2* __restrict__ tokslot,
    const int* __restrict__ prefix, const float* __restrict__ gates,
    float* __restrict__ out) {
  const int w = threadIdx.x >> 6, lane = threadIdx.x & 63;
  const int t = blockIdx.x * 4 + w;
  const int2 s = tokslot[t];
  const int e1 = s.x >> 13, p1 = s.x & 8191;
  const int e2 = s.y >> 13, p2 = s.y & 8191;
  const int r1 = prefix[e1] + p1;
  const int r2 = prefix[e2] + p2;
  const float g1 = gates[(size_t)t * 4 + e1];
  const float g2 = gates[(size_t)t * 4 + e2];
  const ushort4* y1 = (const ushort4*)(yout + (size_t)r1 * 1024);
  const ushort4* y2 = (const ushort4*)(yout + (size_t)r2 * 1024);
  float4* o = (float4*)(out + (size_t)t * 1024);
#pragma unroll
  for (int j = 0; j < 4; ++j) {
    const int c = lane + j * 64;
    ushort4 a = y1[c], b = y2[c];
    float4 r;
    r.x = g1 * bf2f(a.x) + g2 * bf2f(b.x);
    r.y = g1 * bf2f(a.y) + g2 * bf2f(b.y);
    r.z = g1 * bf2f(a.z) + g2 * bf2f(b.z);
    r.w = g1 * bf2f(a.w) + g2 * bf2f(b.w);
    o[c] = r;
  }
}

// ---------------------------------------------------------------------------
// FALLBACK scatter (atomic, split-K x2) — single-buffered R10 version.
// ---------------------------------------------------------------------------
__global__ __launch_bounds__(512) void gemm_scatter_kernel(
    const u16* __restrict__ h, const int* __restrict__ hbase_arr,
    const u16* __restrict__ WT, size_t wts, const int* __restrict__ list,
    const int* __restrict__ cnt_arr, int e0, const float* __restrict__ be2,
    const float* __restrict__ combine, float* __restrict__ out) {
  const int K = 4096;
  const int zslot = blockIdx.z >> 1;
  const int kz = blockIdx.z & 1;
  const int e = e0 + zslot;
  const int cnt = cnt_arr[e];
  const int rb = blockIdx.y;
  if (rb * 128 >= cnt) return;
  const int hbase = hbase_arr[e];
  const int* lst = list + e * 8192;
  const u16* Bt = WT + (size_t)zslot * wts;
  const float* bias = be2 + e * 1024;
  const int koff = kz * 2048;

  __shared__ alignas(16) u16 As[128 * 64];
  __shared__ alignas(16) u16 Bs[256 * 64];
  const int tid = threadIdx.x;
  const int lane = tid & 63;
  const int w = tid >> 6;
  const int wr = w >> 2, wc = w & 3;
  const int bcol = blockIdx.x * 256;

  const int srow = tid >> 3;
  const int jx8 = (((tid & 7) ^ (srow & 7)) << 3);
  const u16* aS[2];
  const u16* bS[4];
#pragma unroll
  for (int i = 0; i < 2; ++i)
    aS[i] = h + (size_t)(hbase + rb * 128 + srow + 64 * i) * K + koff + jx8;
#pragma unroll
  for (int i = 0; i < 4; ++i)
    bS[i] = Bt + (size_t)(bcol + srow + 64 * i) * K + koff + jx8;
  char* AsB = (char*)As;
  char* BsB = (char*)Bs;
  const int dstb = tid * 16;

  f32x4 acc[4][4] = {};
  const int rA = lane & 15;
  const int ksl = lane >> 4;
  const int rx7 = rA & 7;

  const int nk = 2048 >> 6;
  for (int kt = 0; kt < nk; ++kt) {
    const int kb = kt << 6;
    __syncthreads();
#pragma unroll
    for (int i = 0; i < 2; ++i)
      gload_lds16(aS[i] + kb, AsB + i * 8192 + dstb);
#pragma unroll
    for (int i = 0; i < 4; ++i)
      gload_lds16(bS[i] + kb, BsB + i * 8192 + dstb);
    __syncthreads();
#pragma unroll
    for (int s = 0; s < 2; ++s) {
      bf16x8 a[4], b[4];
      const int sl = (((s * 4 + ksl) ^ rx7) << 4);
#pragma unroll
      for (int m = 0; m < 4; ++m)
        a[m] = *(const bf16x8*)(AsB + (wr * 64 + m * 16 + rA) * 128 + sl);
#pragma unroll
      for (int n = 0; n < 4; ++n)
        b[n] = *(const bf16x8*)(BsB + (wc * 64 + n * 16 + rA) * 128 + sl);
#pragma unroll
      for (int m = 0; m < 4; ++m)
#pragma unroll
        for (int n = 0; n < 4; ++n)
          acc[m][n] =
              __builtin_amdgcn_mfma_f32_16x16x32_bf16(a[m], b[n], acc[m][n], 0, 0, 0);
    }
  }

  const int cr = (lane >> 4) * 4;
  const int ccx = lane & 15;
  const bool addb = (kz == 0);
#pragma unroll
  for (int m = 0; m < 4; ++m)
#pragma unroll
    for (int r = 0; r < 4; ++r) {
      const int gl = rb * 128 + wr * 64 + m * 16 + cr + r;
      if (gl >= cnt) continue;
      const int tok = lst[gl];
      const float gcoef = combine[(size_t)tok * 4 + e];
      float* orow = out + (size_t)tok * 1024;
#pragma unroll
      for (int n = 0; n < 4; ++n) {
        const int gc = bcol + wc * 64 + n * 16 + ccx;
        float v = acc[m][n][r];
        if (addb) v += bias[gc];
        atomicAdd(&orow[gc], gcoef * v);
      }
    }
}

// ---------------------------------------------------------------------------
extern "C" void kernel_launch(void* const* d_in, const int* in_sizes, int n_in,
                              void* d_out, int out_size, void* d_ws,
                              size_t ws_size, hipStream_t stream) {
  const float* x = (const float*)d_in[0];
  const float* rW1 = (const float*)d_in[1];
  const float* rb1 = (const float*)d_in[2];
  const float* rW2 = (const float*)d_in[3];
  const float* rb2 = (const float*)d_in[4];
  const float* We1 = (const float*)d_in[5];
  const float* be1 = (const float*)d_in[6];
  const float* We2 = (const float*)d_in[7];
  const float* be2 = (const float*)d_in[8];
  float* out = (float*)d_out;

  const int T = 8192, D = 1024, D2 = 2048, H = 4096, E = 4;
  const size_t WTS = (size_t)H * D;

  char* ws = (char*)d_ws;
  size_t off = 0;
  auto alloc = [&](size_t bytes) {
    char* p = ws + off;
    off = (off + bytes + 255) & ~(size_t)255;
    return p;
  };
  u16* x_hi = (u16*)alloc((size_t)T * D * 2);            // 16 MB
  float* combine = (float*)alloc((size_t)T * 4 * 4);
  int* cnt = (int*)alloc(256);
  int* prefix = cnt + 4;
  int* list = (int*)alloc((size_t)4 * 8192 * 4);
  int2* tokslot = (int2*)alloc((size_t)T * 8);           // 64 KB
  const size_t common_off = off;

  bool merged;
  u16 *We1T, *We2T, *h, *x_lo, *rW1T_hi, *rW1T_lo, *yout;
  float* parts;
  {
    size_t o = common_off;
    auto a2 = [&](size_t bytes) {
      char* p = ws + o;
      o = (o + bytes + 255) & ~(size_t)255;
      return p;
    };
    u16* w1 = (u16*)a2((size_t)4 * WTS * 2);             // 32 MB
    u16* w2 = (u16*)a2((size_t)4 * WTS * 2);             // 32 MB
    char* hreg = a2((size_t)16384 * H * 2 + (2u << 20)); // 128 MB + 2 MB pad
    merged = (o <= ws_size);  // ~211 MB total — fits (R8-R16)
    if (merged) {
      We1T = w1;
      We2T = w2;
      h = (u16*)hreg;
      yout = w1;  // ALIAS: We1T dead after gather-all; yout = 32 MB bf16
      x_lo = (u16*)hreg;                        // 16 MB (dead before h)
      rW1T_hi = (u16*)(hreg + (16u << 20));     // 4 MB
      rW1T_lo = (u16*)(hreg + (20u << 20));     // 4 MB
      parts = (float*)(hreg + (24u << 20));     // 2 MB
    }
  }
  if (!merged) {
    off = common_off;
    We1T = (u16*)alloc(WTS * 2);
    We2T = (u16*)alloc(WTS * 2);
    x_lo = (u16*)alloc((size_t)T * D * 2);
    rW1T_hi = (u16*)alloc((size_t)D2 * D * 2);
    rW1T_lo = (u16*)alloc((size_t)D2 * D * 2);
    parts = (float*)alloc((size_t)16 * T * 4 * 4);
    h = (u16*)alloc((size_t)T * H * 2);
    yout = nullptr;
  }

  hipMemsetAsync(cnt, 0, 32, stream);
  if (!merged) hipMemsetAsync(out, 0, (size_t)T * D * 4, stream);

  dim3 tb(32, 8);

  convert_split_kernel<<<2048, 256, 0, stream>>>(x, x_hi, x_lo, T * D / 4);
  transpose_split_kernel<<<dim3(D2 / 32, D / 32), tb, 0, stream>>>(
      rW1, rW1T_hi, rW1T_lo, D, D2);
  gemm3_router_kernel<<<dim3(16, 64), 256, 0, stream>>>(
      x_hi, x_lo, rW1T_hi, rW1T_lo, D, rb1, rW2, parts);
  topk_kernel<<<T / 256, 256, 0, stream>>>(parts, rb2, combine, cnt, list,
                                           tokslot, T);

  if (merged) {
    prefix_kernel<<<1, 64, 0, stream>>>(cnt, prefix);
    transpose_pair_kernel<<<dim3(8192, 4), tb, 0, stream>>>(
        We1, We2, We1T, We2T, WTS, 0);
    gemm_gather_kernel<<<dim3(16, 64, 4), 512, 0, stream>>>(
        x_hi, We1T, WTS, list, cnt, prefix, 0, be1, h);
    // yout aliases We1T (dead now); scatter: R12 body + XCD-pair remap
    gemm_scatter_y_kernel<<<1024, 512, 0, stream>>>(
        h, prefix, We2T, WTS, cnt, 0, be2, yout);
    combine_kernel<<<T / 4, 256, 0, stream>>>(yout, tokslot, prefix, combine,
                                              out);
  } else {
    for (int e = 0; e < E; ++e) {
      transpose_pair_kernel<<<dim3(8192, 1), tb, 0, stream>>>(
          We1, We2, We1T, We2T, 0, e);
      gemm_gather_kernel<<<dim3(16, 64, 1), 512, 0, stream>>>(
          x_hi, We1T, 0, list, cnt, prefix /*zeros*/, e, be1, h);
      gemm_scatter_kernel<<<dim3(4, 64, 2), 512, 0, stream>>>(
          h, prefix /*zeros*/, We2T, 0, list, cnt, e, be2, combine, out);
    }
  }
}